// Round 10
// baseline (174.492 us; speedup 1.0000x reference)
//
#include <hip/hip_runtime.h>
#include <stdint.h>

#define B_ 2
#define S_ 2048
#define E_ 1024
#define H_ 16
#define HD_ 64
#define N_ (B_*S_)
#define BH_ (B_*H_)
#define GAMMA 0.01f

typedef __attribute__((ext_vector_type(8))) short bf16x8;
typedef __attribute__((ext_vector_type(4))) float f32x4;
typedef __attribute__((ext_vector_type(2))) float f32x2;
typedef __attribute__((ext_vector_type(16))) float f32x16;
typedef __attribute__((ext_vector_type(4))) unsigned int u32x4;
typedef unsigned short u16;
typedef unsigned int u32;

// byte-level XOR swizzle within a 128B row
#define SWZ(row, kb) ((kb) ^ (((row)&7)<<4))

__device__ __forceinline__ u16 f2bf(float f){
  union { float f; u32 u; } v; v.f = f;
  return (u16)((v.u + 0x7FFFu + ((v.u>>16)&1u)) >> 16);
}

__device__ __forceinline__ float bf2f(u16 u){
  union { u32 u; float f; } v; v.u = ((u32)u)<<16; return v.f;
}

__device__ __forceinline__ u32 cvt_pk_bf16(float lo, float hi){
  u32 r; asm("v_cvt_pk_bf16_f32 %0, %1, %2" : "=v"(r) : "v"(lo), "v"(hi)); return r;
}

__device__ __forceinline__ uint4 pack8(float4 a, float4 b){
  uint4 r;
  r.x = (u32)f2bf(a.x) | ((u32)f2bf(a.y)<<16);
  r.y = (u32)f2bf(a.z) | ((u32)f2bf(a.w)<<16);
  r.z = (u32)f2bf(b.x) | ((u32)f2bf(b.y)<<16);
  r.w = (u32)f2bf(b.z) | ((u32)f2bf(b.w)<<16);
  return r;
}

__device__ __forceinline__ bf16x8 ldfrag(const unsigned char* base, int row, int kbyte){
  return *reinterpret_cast<const bf16x8*>(base + row*128 + SWZ(row, kbyte));
}
// V tile has 256B rows; 16-slot swizzle
__device__ __forceinline__ bf16x8 ldfragV(const unsigned char* base, int row, int col){
  return *reinterpret_cast<const bf16x8*>(base + row*256 + (col ^ ((row&15)<<4)));
}

// async global->LDS, 16B/lane; LDS dest = wave-uniform base + lane*16 (linear),
// swizzling achieved by permuting the per-lane SOURCE address
__device__ __forceinline__ void gl_lds16(const void* g, void* l){
  __builtin_amdgcn_global_load_lds(
      (const __attribute__((address_space(1))) unsigned int*)g,
      (__attribute__((address_space(3))) unsigned int*)l, 16, 0, 0);
}

// ---------------- K1: per-head QKV projection + xnorm(v), V transposed ----------------
// blockIdx.y >= H_: weight-conversion slabs (folded former k_cvt)
__device__ __forceinline__ void proj_mfma(const unsigned char* X, const unsigned char* W,
                                          int wid, int l15, int g4, f32x4 acc[4])
{
  f32x4 z = {0.f,0.f,0.f,0.f};
  acc[0]=z; acc[1]=z; acc[2]=z; acc[3]=z;
  #pragma unroll
  for (int kk=0;kk<2;++kk){
    int kbyte = kk*64 + g4*16;
    bf16x8 a = ldfrag(X, wid*16 + l15, kbyte);
    #pragma unroll
    for (int t=0;t<4;++t){
      bf16x8 w = ldfrag(W, t*16 + l15, kbyte);
      acc[t] = __builtin_amdgcn_mfma_f32_16x16x32_bf16(a, w, acc[t], 0, 0, 0);
    }
  }
}

__global__ __launch_bounds__(256) void k_proj(
    const float* __restrict__ qin, const float* __restrict__ kin, const float* __restrict__ vin,
    const float* __restrict__ Wq, const float* __restrict__ Wk, const float* __restrict__ Wv,
    u16* __restrict__ qp, u16* __restrict__ kp, u16* __restrict__ vnT,
    const float* __restrict__ Wo, const float* __restrict__ Wsq,
    u16* __restrict__ wo16, u16* __restrict__ wsq16)
{
  __shared__ alignas(16) unsigned char sm[57344];
  if (blockIdx.y >= H_){
    int cblk = (blockIdx.y - H_)*64 + blockIdx.x;
    int n4 = (E_*E_)/4;
    for (int i = cblk*256 + threadIdx.x; i < 2*n4; i += 128*256){
      const float4* src; ushort4* dst; int j;
      if (i < n4){ src=(const float4*)Wo;  dst=(ushort4*)wo16;  j=i; }
      else       { src=(const float4*)Wsq; dst=(ushort4*)wsq16; j=i-n4; }
      float4 v = src[j];
      ushort4 p; p.x=f2bf(v.x); p.y=f2bf(v.y); p.z=f2bf(v.z); p.w=f2bf(v.w);
      dst[j] = p;
    }
    return;
  }
  const int XQ=0, XK=8192, XV=16384, WQS=24576, WKS=32768, WVS=40960, VT=49152;
  int tid = threadIdx.x, lane = tid&63, wid = tid>>6;
  int l15 = lane&15, g4 = lane>>4;
  int tb = blockIdx.x*64;
  int h  = blockIdx.y;
  int b  = tb >> 11;
  int sbase = tb & 2047;
  int bh = b*H_ + h;

  {
    int rl = tid>>2;
    int d0 = (tid&3)*16;
    const float* xs[3] = { qin, kin, vin };
    const float* wsrc[3] = { Wq, Wk, Wv };
    const int xoff[3] = {XQ,XK,XV}, woff[3] = {WQS,WKS,WVS};
    #pragma unroll
    for (int m3=0;m3<3;++m3){
      const float4* gx = reinterpret_cast<const float4*>(xs[m3] + (size_t)(tb+rl)*E_ + h*HD_ + d0);
      float4 a=gx[0], bb=gx[1], c=gx[2], d=gx[3];
      *(uint4*)(sm + xoff[m3] + rl*128 + SWZ(rl, d0*2))    = pack8(a,bb);
      *(uint4*)(sm + xoff[m3] + rl*128 + SWZ(rl, d0*2+16)) = pack8(c,d);
      const float4* gw = reinterpret_cast<const float4*>(wsrc[m3] + rl*64 + d0);
      float4 e=gw[0], f=gw[1], g2=gw[2], h2=gw[3];
      *(uint4*)(sm + woff[m3] + rl*128 + SWZ(rl, d0*2))    = pack8(e,f);
      *(uint4*)(sm + woff[m3] + rl*128 + SWZ(rl, d0*2+16)) = pack8(g2,h2);
    }
  }
  __syncthreads();

  f32x4 acc[4];
  proj_mfma(sm+XQ, sm+WQS, wid, l15, g4, acc);
  #pragma unroll
  for (int t=0;t<4;++t)
    #pragma unroll
    for (int r=0;r<4;++r){
      int tokl = wid*16 + g4*4 + r;
      qp[((size_t)bh*S_ + sbase + tokl)*HD_ + t*16 + l15] = f2bf(acc[t][r]);
    }
  proj_mfma(sm+XK, sm+WKS, wid, l15, g4, acc);
  #pragma unroll
  for (int t=0;t<4;++t)
    #pragma unroll
    for (int r=0;r<4;++r){
      int tokl = wid*16 + g4*4 + r;
      kp[((size_t)bh*S_ + sbase + tokl)*HD_ + t*16 + l15] = f2bf(acc[t][r]);
    }
  proj_mfma(sm+XV, sm+WVS, wid, l15, g4, acc);
  {
    float p4r[4] = {0.f,0.f,0.f,0.f};
    #pragma unroll
    for (int t=0;t<4;++t)
      #pragma unroll
      for (int r=0;r<4;++r){ float e = acc[t][r]; float e2 = e*e; p4r[r] += e2*e2; }
    #pragma unroll
    for (int r=0;r<4;++r){
      float p = p4r[r];
      p += __shfl_xor(p,1); p += __shfl_xor(p,2); p += __shfl_xor(p,4); p += __shfl_xor(p,8);
      p4r[r] = GAMMA / sqrtf(sqrtf(p));
    }
    #pragma unroll
    for (int t=0;t<4;++t)
      #pragma unroll
      for (int r=0;r<4;++r){
        int tokl = wid*16 + g4*4 + r;
        int dd = t*16 + l15;
        *(u16*)(sm + VT + dd*128 + SWZ(dd, tokl*2)) = f2bf(acc[t][r] * p4r[r]);
      }
  }
  __syncthreads();
  {
    int dd = tid>>2; int c2 = tid&3;
    size_t gbase = ((size_t)bh*HD_ + dd)*S_ + sbase + c2*16;
    uint4 v0 = *(const uint4*)(sm + VT + dd*128 + SWZ(dd, c2*32));
    uint4 v1 = *(const uint4*)(sm + VT + dd*128 + SWZ(dd, c2*32+16));
    *(uint4*)(vnT + gbase)     = v0;
    *(uint4*)(vnT + gbase + 8) = v1;
  }
}

// ---------------- K2: flash attention, 8 waves (2qi x 4kj), KVBLK=128 ----------------
// Block: 512 threads, 128 q-rows. Wave = 64q (Fq=2) x 32-key quarter: 8 QK + 8 PV
// MFMAs per tile (2:1 MFMA:ds_read kept), chains half as long, 16 waves/CU =
// 4 waves/SIMD (2x TLP vs round 9). 2 x 32KB LDS dbuf, 2 barriers/tile, vmcnt(4).
// Epilogue: 3-stage LDS tree reduces the 4 kj partials.
__global__ __launch_bounds__(512, 4) void k_attn(
    const u16* __restrict__ qp, const u16* __restrict__ kp,
    const u16* __restrict__ vnT, u16* __restrict__ ao)
{
  __shared__ alignas(128) unsigned char sm[65536];   // 2 x (K 16KB + V 16KB); reused by reduce
  __shared__ float p4s[2][256];
  char* smc = (char*)sm;
  int tid = threadIdx.x, lane = tid&63, wv = tid>>6;
  int l31 = lane&31, hi = lane>>5;
  int qi = wv>>2, kj = wv&3;
  int L = blockIdx.x;
  int xcd = L&7, iw = L>>3;            // iw 0..63
  int bh = xcd*4 + (iw>>4);            // consecutive iw share bh (L1/L2 reuse)
  int qx = iw&15;
  int qb = qx*128;
  int b = bh>>4, h = bh&15;
  const u16* Kb = kp  + (size_t)bh*S_*HD_;
  const u16* Vb = vnT + (size_t)bh*HD_*S_;
  const u16* Qb = qp  + (size_t)bh*S_*HD_;
  int q0 = qb + qi*64;

  // Q fragments (B-operand): 2 q-frags of 32 rows each
  bf16x8 qf[2][4];
  #pragma unroll
  for (int f=0;f<2;++f)
    #pragma unroll
    for (int kk=0;kk<4;++kk)
      qf[f][kk] = *reinterpret_cast<const bf16x8*>(Qb + (size_t)(q0 + f*32 + l31)*HD_ + kk*16 + hi*8);

  f32x16 z16 = {};
  f32x16 o[2][2];
  #pragma unroll
  for (int f=0;f<2;++f){ o[f][0] = z16; o[f][1] = z16; }
  f32x2 p4a[2] = {{0.f,0.f},{0.f,0.f}};

  // staging sources (pre-swizzled cols). K tile [128][128B]; V tile [64][256B].
  // 8 waves x 4 gl_lds x 1KB = 32KB per tile buffer.
  const char* kSrcC[2]; const char* vSrcC[2];
  #pragma unroll
  for (int c=0;c<2;++c){
    int off = wv*2048 + c*1024 + lane*16;
    int rk = off>>7, ck = off&127;
    kSrcC[c] = (const char*)Kb + (size_t)rk*128 + (ck ^ ((rk&7)<<4));
    int rv = off>>8, cv = off&255;
    vSrcC[c] = (const char*)Vb + (size_t)rv*4096 + (cv ^ ((rv&15)<<4));
  }

  auto STAGE = [&](int bsel, int kt){
    char* db = smc + bsel*32768 + wv*2048;
    #pragma unroll
    for (int c=0;c<2;++c) gl_lds16(kSrcC[c] + (size_t)kt*16384, db + c*1024);
    #pragma unroll
    for (int c=0;c<2;++c) gl_lds16(vSrcC[c] + (size_t)kt*256,   db + 16384 + c*1024);
  };

  auto PACK = [&](const f32x16& e, u32 (&w)[4][2], f32x2& pa){
    #pragma unroll
    for (int j=0;j<8;++j){
      const int g=j>>1, i=j&1;
      float a = e[4*g+2*i], c = e[4*g+2*i+1];
      f32x2 pr = {a, c};
      f32x2 e2;
      asm("v_pk_mul_f32 %0, %1, %1" : "=v"(e2) : "v"(pr));
      asm("v_pk_fma_f32 %0, %1, %1, %0" : "+v"(pa) : "v"(e2));
      w[g][i] = cvt_pk_bf16(a, c);
    }
  };
  auto AFRAG = [&](u32 (&w)[4][2], int s) -> bf16x8 {
    u32 a0 = w[2*s][0], b0 = w[2*s+1][0];
    u32 a1 = w[2*s][1], b1 = w[2*s+1][1];
    asm("v_permlane32_swap_b32 %0, %1" : "+v"(a0), "+v"(b0));
    asm("v_permlane32_swap_b32 %0, %1" : "+v"(a1), "+v"(b1));
    u32x4 fw = {a0, a1, b0, b1};
    return __builtin_bit_cast(bf16x8, fw);
  };

  const int NT = S_/128;   // 16
  STAGE(0, 0); STAGE(1, 1);

  u32 w0[4][2], w1[4][2];

  #pragma unroll 1
  for (int t=0; t<NT; ++t){
    if (t < NT-1) { asm volatile("s_waitcnt vmcnt(4)" ::: "memory"); }
    else          { asm volatile("s_waitcnt vmcnt(0)" ::: "memory"); }
    __builtin_amdgcn_s_barrier();
    asm volatile("" ::: "memory");
    const unsigned char* K_ = sm + (t&1)*32768;
    const unsigned char* V_ = K_ + 16384;

    // QK^T: wave's 32-key quarter (keys kj*32..+31 of this tile)
    bf16x8 ka[4];
    #pragma unroll
    for (int kk=0;kk<4;++kk) ka[kk] = ldfrag(K_, kj*32 + l31, kk*32 + hi*16);
    f32x16 e0 = z16, e1 = z16;
    __builtin_amdgcn_s_setprio(1);
    #pragma unroll
    for (int kk=0;kk<4;++kk){
      e0 = __builtin_amdgcn_mfma_f32_32x32x16_bf16(ka[kk], qf[0][kk], e0, 0,0,0);
      e1 = __builtin_amdgcn_mfma_f32_32x32x16_bf16(ka[kk], qf[1][kk], e1, 0,0,0);
    }
    __builtin_amdgcn_s_setprio(0);

    PACK(e0, w0, p4a[0]);
    PACK(e1, w1, p4a[1]);

    // PV over the same 32-key quarter: byte cols kj*64 .. +63 of V tile
    bf16x8 vb[2][2];
    #pragma unroll
    for (int s=0;s<2;++s){
      vb[s][0] = ldfragV(V_, l31,    kj*64 + s*32 + hi*16);
      vb[s][1] = ldfragV(V_, 32+l31, kj*64 + s*32 + hi*16);
    }
    __builtin_amdgcn_s_setprio(1);
    #pragma unroll
    for (int s=0;s<2;++s){
      bf16x8 ef0 = AFRAG(w0, s);
      bf16x8 ef1 = AFRAG(w1, s);
      o[0][0] = __builtin_amdgcn_mfma_f32_32x32x16_bf16(ef0, vb[s][0], o[0][0], 0,0,0);
      o[0][1] = __builtin_amdgcn_mfma_f32_32x32x16_bf16(ef0, vb[s][1], o[0][1], 0,0,0);
      o[1][0] = __builtin_amdgcn_mfma_f32_32x32x16_bf16(ef1, vb[s][0], o[1][0], 0,0,0);
      o[1][1] = __builtin_amdgcn_mfma_f32_32x32x16_bf16(ef1, vb[s][1], o[1][1], 0,0,0);
    }
    __builtin_amdgcn_s_setprio(0);

    asm volatile("" ::: "memory");
    __builtin_amdgcn_s_barrier();      // everyone done reading buf[t&1]
    asm volatile("" ::: "memory");
    if (t+2 < NT) STAGE(t&1, t+2);
  }

  // ---- 3-stage cross-wave (4 kj) reduce via LDS, then L4 scale + store ----
  float p4f[2];
  #pragma unroll
  for (int f=0;f<2;++f) p4f[f] = p4a[f].x + p4a[f].y;

  auto writeO = [&](int sl){
    float* base = (float*)(smc + sl*32768);
    #pragma unroll
    for (int f=0;f<2;++f){
      #pragma unroll
      for (int ds=0;ds<2;++ds){
        float* dst = base + ((((qi*2+f)*2+ds)*64 + lane)*16);
        #pragma unroll
        for (int r4=0;r4<4;++r4)
          *(float4*)(dst + r4*4) = make_float4(o[f][ds][r4*4],o[f][ds][r4*4+1],o[f][ds][r4*4+2],o[f][ds][r4*4+3]);
      }
      p4s[sl][(qi*2+f)*64 + lane] = p4f[f];
    }
  };
  auto accO = [&](int sl){
    const float* base = (const float*)(smc + sl*32768);
    #pragma unroll
    for (int f=0;f<2;++f){
      #pragma unroll
      for (int ds=0;ds<2;++ds){
        const float* srcp = base + ((((qi*2+f)*2+ds)*64 + lane)*16);
        #pragma unroll
        for (int r4=0;r4<4;++r4){
          float4 t = *(const float4*)(srcp + r4*4);
          o[f][ds][r4*4]+=t.x; o[f][ds][r4*4+1]+=t.y; o[f][ds][r4*4+2]+=t.z; o[f][ds][r4*4+3]+=t.w;
        }
      }
      p4f[f] += p4s[sl][(qi*2+f)*64 + lane];
    }
  };

  __syncthreads();                      // main-loop LDS reads complete
  if (kj==1) writeO(0);
  if (kj==3) writeO(1);
  __syncthreads();
  if (kj==0) accO(0);
  if (kj==2) accO(1);
  __syncthreads();
  if (kj==2) writeO(0);
  __syncthreads();
  if (kj==0){
    accO(0);
    #pragma unroll
    for (int f=0;f<2;++f) p4f[f] += __shfl_xor(p4f[f], 32);
    float sc0 = GAMMA * rsqrtf(sqrtf(p4f[0]));
    float sc1 = GAMMA * rsqrtf(sqrtf(p4f[1]));
    #pragma unroll
    for (int f=0;f<2;++f){
      #pragma unroll
      for (int r=0;r<16;++r){
        int qrow = (r&3) + 8*(r>>2) + 4*hi;
        float scr = __shfl(f==0 ? sc0 : sc1, qrow);
        size_t n = (size_t)b*S_ + q0 + f*32 + qrow;
        u16* dst = ao + n*E_ + h*HD_;
        dst[l31]    = f2bf(o[f][0][r] * scr);
        dst[32+l31] = f2bf(o[f][1][r] * scr);
      }
    }
  }
}

// ---------------- K3/K5: 128x64-tile bf16 GEMM (y = A @ Bw^T), T3/T4 pipeline ----------------
template<int MODE>
__global__ __launch_bounds__(256, 2) void k_gemm(
    const u16* __restrict__ A, const u16* __restrict__ Bw,
    const float* __restrict__ bias, const float* __restrict__ auxf,
    const u16* __restrict__ aux16, float* __restrict__ out32, u16* __restrict__ out16)
{
  __shared__ alignas(128) unsigned char sm[73728];   // 3 x (A 16KB + B 8KB)
  char* smc = (char*)sm;
  int tid = threadIdx.x, lane = tid&63, wv = tid>>6;
  int l31 = lane&31, hi = lane>>5;
  int wr = wv>>1, wc = wv&1;
  int LL = (blockIdx.x & 7)*64 + (blockIdx.x >> 3);   // 512 = 8 XCD x 64
  int mt = LL >> 4, nt = LL & 15;
  int m0 = mt*128, n0 = nt*64;

  int ric  = lane>>3;
  int colb = ((lane&7)*16) ^ ((ric&7)<<4);
  const char* aSrc[4]; const char* bSrc[2];
  #pragma unroll
  for (int j=0;j<4;++j)
    aSrc[j] = (const char*)A  + ((size_t)(m0 + wv*32 + 8*j + ric)*E_)*2 + colb;
  #pragma unroll
  for (int j=0;j<2;++j)
    bSrc[j] = (const char*)Bw + ((size_t)(n0 + wv*16 + 8*j + ric)*E_)*2 + colb;

  auto STAGE = [&](int bsel, int t){
    char* db = smc + bsel*24576;
    size_t kb2 = (size_t)t*128;
    #pragma unroll
    for (int j=0;j<4;++j) gl_lds16(aSrc[j] + kb2, db + (wv*4+j)*1024);
    #pragma unroll
    for (int j=0;j<2;++j) gl_lds16(bSrc[j] + kb2, db + 16384 + (wv*2+j)*1024);
  };

  f32x16 acc[2] = {{}, {}};

  const int NK = E_/64;   // 16
  STAGE(0, 0); STAGE(1, 1);

  #pragma unroll 1
  for (int t=0; t<NK; ++t){
    if (t < NK-1) { asm volatile("s_waitcnt vmcnt(6)" ::: "memory"); }
    else          { asm volatile("s_waitcnt vmcnt(0)" ::: "memory"); }
    __builtin_amdgcn_s_barrier();
    asm volatile("" ::: "memory");
    if (t+2 < NK) STAGE((t+2)%3, t+2);

    const unsigned char* Ap_ = sm + (t%3)*24576;
    const unsigned char* Bp_ = Ap_ + 16384;
    #pragma unroll
    for (int kk=0;kk<4;++kk){
      bf16x8 bfr = ldfrag(Bp_, wc*32 + l31, kk*32 + hi*16);
      bf16x8 af0 = ldfrag(Ap_, wr*64 + l31,      kk*32 + hi*16);
      bf16x8 af1 = ldfrag(Ap_, wr*64 + 32 + l31, kk*32 + hi*16);
      __builtin_amdgcn_s_setprio(1);
      acc[0] = __builtin_amdgcn_mfma_f32_32x32x16_bf16(af0, bfr, acc[0], 0,0,0);
      acc[1] = __builtin_amdgcn_mfma_f32_32x32x16_bf16(af1, bfr, acc[1], 0,0,0);
      __builtin_amdgcn_s_setprio(0);
    }
  }

  int col = n0 + wc*32 + l31;
  float bi = bias[col];
  #pragma unroll
  for (int rg=0;rg<2;++rg)
    #pragma unroll
    for (int r=0;r<16;++r){
      int mrow = m0 + wr*64 + rg*32 + (r&3) + 8*(r>>2) + 4*hi;
      size_t idx = (size_t)mrow*E_ + col;
      float v = acc[rg][r] + bi;
      if (MODE == 0){
        out16[idx] = f2bf(v + auxf[idx]);
      } else {
        float gg = 1.f/(1.f + __expf(-v));
        out32[idx] = bf2f(aux16[idx]) * gg;
      }
    }
}

// ---------------- K4: LayerNorm over embed dim; bf16 in -> bf16 out ----------------
__global__ __launch_bounds__(256) void k_ln(
    const u16* __restrict__ xin, const float* __restrict__ lnw, const float* __restrict__ lnb,
    u16* __restrict__ xout)
{
  __shared__ float red[8];
  __shared__ float stats[2];
  int row = blockIdx.x, tid = threadIdx.x;
  ushort4 xr = reinterpret_cast<const ushort4*>(xin + (size_t)row*E_)[tid];
  float x0 = bf2f(xr.x), x1 = bf2f(xr.y), x2 = bf2f(xr.z), x3 = bf2f(xr.w);
  float s  = x0 + x1 + x2 + x3;
  float s2 = x0*x0 + x1*x1 + x2*x2 + x3*x3;
  #pragma unroll
  for (int m=1;m<64;m<<=1){ s += __shfl_xor(s,m); s2 += __shfl_xor(s2,m); }
  if ((tid&63)==0){ red[tid>>6] = s; red[4+(tid>>6)] = s2; }
  __syncthreads();
  if (tid==0){
    float ts  = red[0]+red[1]+red[2]+red[3];
    float ts2 = red[4]+red[5]+red[6]+red[7];
    float mu  = ts * (1.f/E_);
    float var = ts2 * (1.f/E_) - mu*mu;
    stats[0] = mu; stats[1] = rsqrtf(var + 1e-5f);
  }
  __syncthreads();
  float mu = stats[0], rstd = stats[1];
  float4 w  = reinterpret_cast<const float4*>(lnw)[tid];
  float4 bb = reinterpret_cast<const float4*>(lnb)[tid];
  ushort4 p;
  p.x = f2bf((x0-mu)*rstd*w.x + bb.x);
  p.y = f2bf((x1-mu)*rstd*w.y + bb.y);
  p.z = f2bf((x2-mu)*rstd*w.z + bb.z);
  p.w = f2bf((x3-mu)*rstd*w.w + bb.w);
  reinterpret_cast<ushort4*>(xout + (size_t)row*E_)[tid] = p;
}

// ---------------- host launch ----------------
extern "C" void kernel_launch(void* const* d_in, const int* in_sizes, int n_in,
                              void* d_out, int out_size, void* d_ws, size_t ws_size,
                              hipStream_t stream)
{
  const float* value = (const float*)d_in[0];
  const float* key   = (const float*)d_in[1];
  const float* query = (const float*)d_in[2];
  const float* Wq    = (const float*)d_in[3];
  const float* Wk    = (const float*)d_in[4];
  const float* Wv    = (const float*)d_in[5];
  const float* Wo    = (const float*)d_in[6];
  const float* bo    = (const float*)d_in[7];
  const float* lnw   = (const float*)d_in[8];
  const float* lnb   = (const float*)d_in[9];
  const float* Wsq   = (const float*)d_in[10];
  const float* bsq   = (const float*)d_in[11];
  float* out = (float*)d_out;

  char* ws = (char*)d_ws;
  const size_t MB = 1ull<<20;
  u16*   qp     = (u16*)(ws + 0*MB);    // K1->K2
  u16*   kp     = (u16*)(ws + 8*MB);    // K1->K2
  u16*   vnT    = (u16*)(ws + 16*MB);   // K1->K2
  u16*   ao     = (u16*)(ws + 24*MB);   // K2->K3 (8MB)
  u16*   xres16 = (u16*)(ws + 8*MB);    // K3->K4 (8MB, over kp)
  u16*   x16    = (u16*)(ws + 16*MB);   // K4->K5 (8MB, over vnT)
  u16*   wo16   = (u16*)(ws + 48*MB);
  u16*   wsq16  = (u16*)(ws + 50*MB);

  k_proj<<<dim3(N_/64, H_+2), 256, 0, stream>>>(query, key, value, Wq, Wk, Wv,
                                                qp, kp, vnT, Wo, Wsq, wo16, wsq16);
  k_attn<<<512, 512, 0, stream>>>(qp, kp, vnT, ao);
  k_gemm<0><<<512, 256, 0, stream>>>(ao, wo16, bo, query, (const u16*)nullptr, (float*)nullptr, xres16);
  k_ln  <<<N_, 256, 0, stream>>>(xres16, lnw, lnb, x16);
  k_gemm<1><<<512, 256, 0, stream>>>(x16, wsq16, bsq, (const float*)nullptr, x16, out, (u16*)nullptr);
}

// Round 11
// 123.021 us; speedup vs baseline: 1.4184x; 1.4184x over previous
//
#include <hip/hip_runtime.h>
#include <stdint.h>

#define B_ 2
#define S_ 2048
#define E_ 1024
#define H_ 16
#define HD_ 64
#define N_ (B_*S_)
#define BH_ (B_*H_)
#define GAMMA 0.01f

typedef __attribute__((ext_vector_type(8))) short bf16x8;
typedef __attribute__((ext_vector_type(4))) float f32x4;
typedef __attribute__((ext_vector_type(2))) float f32x2;
typedef __attribute__((ext_vector_type(16))) float f32x16;
typedef __attribute__((ext_vector_type(4))) unsigned int u32x4;
typedef unsigned short u16;
typedef unsigned int u32;

// byte-level XOR swizzle within a 128B row
#define SWZ(row, kb) ((kb) ^ (((row)&7)<<4))

__device__ __forceinline__ u16 f2bf(float f){
  union { float f; u32 u; } v; v.f = f;
  return (u16)((v.u + 0x7FFFu + ((v.u>>16)&1u)) >> 16);
}

__device__ __forceinline__ float bf2f(u16 u){
  union { u32 u; float f; } v; v.u = ((u32)u)<<16; return v.f;
}

__device__ __forceinline__ u32 cvt_pk_bf16(float lo, float hi){
  u32 r; asm("v_cvt_pk_bf16_f32 %0, %1, %2" : "=v"(r) : "v"(lo), "v"(hi)); return r;
}

__device__ __forceinline__ uint4 pack8(float4 a, float4 b){
  uint4 r;
  r.x = (u32)f2bf(a.x) | ((u32)f2bf(a.y)<<16);
  r.y = (u32)f2bf(a.z) | ((u32)f2bf(a.w)<<16);
  r.z = (u32)f2bf(b.x) | ((u32)f2bf(b.y)<<16);
  r.w = (u32)f2bf(b.z) | ((u32)f2bf(b.w)<<16);
  return r;
}

__device__ __forceinline__ bf16x8 ldfrag(const unsigned char* base, int row, int kbyte){
  return *reinterpret_cast<const bf16x8*>(base + row*128 + SWZ(row, kbyte));
}
// V tile has 256B rows; 16-slot swizzle
__device__ __forceinline__ bf16x8 ldfragV(const unsigned char* base, int row, int col){
  return *reinterpret_cast<const bf16x8*>(base + row*256 + (col ^ ((row&15)<<4)));
}

// async global->LDS, 16B/lane; LDS dest = wave-uniform base + lane*16 (linear),
// swizzling achieved by permuting the per-lane SOURCE address
__device__ __forceinline__ void gl_lds16(const void* g, void* l){
  __builtin_amdgcn_global_load_lds(
      (const __attribute__((address_space(1))) unsigned int*)g,
      (__attribute__((address_space(3))) unsigned int*)l, 16, 0, 0);
}

// ---------------- K1: per-head QKV projection + xnorm(v), V transposed ----------------
// blockIdx.y >= H_: weight-conversion slabs (folded former k_cvt)
__device__ __forceinline__ void proj_mfma(const unsigned char* X, const unsigned char* W,
                                          int wid, int l15, int g4, f32x4 acc[4])
{
  f32x4 z = {0.f,0.f,0.f,0.f};
  acc[0]=z; acc[1]=z; acc[2]=z; acc[3]=z;
  #pragma unroll
  for (int kk=0;kk<2;++kk){
    int kbyte = kk*64 + g4*16;
    bf16x8 a = ldfrag(X, wid*16 + l15, kbyte);
    #pragma unroll
    for (int t=0;t<4;++t){
      bf16x8 w = ldfrag(W, t*16 + l15, kbyte);
      acc[t] = __builtin_amdgcn_mfma_f32_16x16x32_bf16(a, w, acc[t], 0, 0, 0);
    }
  }
}

__global__ __launch_bounds__(256) void k_proj(
    const float* __restrict__ qin, const float* __restrict__ kin, const float* __restrict__ vin,
    const float* __restrict__ Wq, const float* __restrict__ Wk, const float* __restrict__ Wv,
    u16* __restrict__ qp, u16* __restrict__ kp, u16* __restrict__ vnT,
    const float* __restrict__ Wo, const float* __restrict__ Wsq,
    u16* __restrict__ wo16, u16* __restrict__ wsq16)
{
  __shared__ alignas(16) unsigned char sm[57344];
  if (blockIdx.y >= H_){
    int cblk = (blockIdx.y - H_)*64 + blockIdx.x;
    int n4 = (E_*E_)/4;
    for (int i = cblk*256 + threadIdx.x; i < 2*n4; i += 128*256){
      const float4* src; ushort4* dst; int j;
      if (i < n4){ src=(const float4*)Wo;  dst=(ushort4*)wo16;  j=i; }
      else       { src=(const float4*)Wsq; dst=(ushort4*)wsq16; j=i-n4; }
      float4 v = src[j];
      ushort4 p; p.x=f2bf(v.x); p.y=f2bf(v.y); p.z=f2bf(v.z); p.w=f2bf(v.w);
      dst[j] = p;
    }
    return;
  }
  const int XQ=0, XK=8192, XV=16384, WQS=24576, WKS=32768, WVS=40960, VT=49152;
  int tid = threadIdx.x, lane = tid&63, wid = tid>>6;
  int l15 = lane&15, g4 = lane>>4;
  int tb = blockIdx.x*64;
  int h  = blockIdx.y;
  int b  = tb >> 11;
  int sbase = tb & 2047;
  int bh = b*H_ + h;

  {
    int rl = tid>>2;
    int d0 = (tid&3)*16;
    const float* xs[3] = { qin, kin, vin };
    const float* wsrc[3] = { Wq, Wk, Wv };
    const int xoff[3] = {XQ,XK,XV}, woff[3] = {WQS,WKS,WVS};
    #pragma unroll
    for (int m3=0;m3<3;++m3){
      const float4* gx = reinterpret_cast<const float4*>(xs[m3] + (size_t)(tb+rl)*E_ + h*HD_ + d0);
      float4 a=gx[0], bb=gx[1], c=gx[2], d=gx[3];
      *(uint4*)(sm + xoff[m3] + rl*128 + SWZ(rl, d0*2))    = pack8(a,bb);
      *(uint4*)(sm + xoff[m3] + rl*128 + SWZ(rl, d0*2+16)) = pack8(c,d);
      const float4* gw = reinterpret_cast<const float4*>(wsrc[m3] + rl*64 + d0);
      float4 e=gw[0], f=gw[1], g2=gw[2], h2=gw[3];
      *(uint4*)(sm + woff[m3] + rl*128 + SWZ(rl, d0*2))    = pack8(e,f);
      *(uint4*)(sm + woff[m3] + rl*128 + SWZ(rl, d0*2+16)) = pack8(g2,h2);
    }
  }
  __syncthreads();

  f32x4 acc[4];
  proj_mfma(sm+XQ, sm+WQS, wid, l15, g4, acc);
  #pragma unroll
  for (int t=0;t<4;++t)
    #pragma unroll
    for (int r=0;r<4;++r){
      int tokl = wid*16 + g4*4 + r;
      qp[((size_t)bh*S_ + sbase + tokl)*HD_ + t*16 + l15] = f2bf(acc[t][r]);
    }
  proj_mfma(sm+XK, sm+WKS, wid, l15, g4, acc);
  #pragma unroll
  for (int t=0;t<4;++t)
    #pragma unroll
    for (int r=0;r<4;++r){
      int tokl = wid*16 + g4*4 + r;
      kp[((size_t)bh*S_ + sbase + tokl)*HD_ + t*16 + l15] = f2bf(acc[t][r]);
    }
  proj_mfma(sm+XV, sm+WVS, wid, l15, g4, acc);
  {
    float p4r[4] = {0.f,0.f,0.f,0.f};
    #pragma unroll
    for (int t=0;t<4;++t)
      #pragma unroll
      for (int r=0;r<4;++r){ float e = acc[t][r]; float e2 = e*e; p4r[r] += e2*e2; }
    #pragma unroll
    for (int r=0;r<4;++r){
      float p = p4r[r];
      p += __shfl_xor(p,1); p += __shfl_xor(p,2); p += __shfl_xor(p,4); p += __shfl_xor(p,8);
      p4r[r] = GAMMA / sqrtf(sqrtf(p));
    }
    #pragma unroll
    for (int t=0;t<4;++t)
      #pragma unroll
      for (int r=0;r<4;++r){
        int tokl = wid*16 + g4*4 + r;
        int dd = t*16 + l15;
        *(u16*)(sm + VT + dd*128 + SWZ(dd, tokl*2)) = f2bf(acc[t][r] * p4r[r]);
      }
  }
  __syncthreads();
  {
    int dd = tid>>2; int c2 = tid&3;
    size_t gbase = ((size_t)bh*HD_ + dd)*S_ + sbase + c2*16;
    uint4 v0 = *(const uint4*)(sm + VT + dd*128 + SWZ(dd, c2*32));
    uint4 v1 = *(const uint4*)(sm + VT + dd*128 + SWZ(dd, c2*32+16));
    *(uint4*)(vnT + gbase)     = v0;
    *(uint4*)(vnT + gbase + 8) = v1;
  }
}

// ---------------- K2: flash attention, 8 waves (2qi x 4kj), KVBLK=128 ----------------
// Round-10 structure; launch_bounds fixed to (512,2) so the allocator can use the
// ~110 VGPRs the per-thread state needs (round 10's (512,4) capped at 64 -> spill,
// FETCH 273MB). 2 blocks/CU x 8 waves = 4 waves/SIMD, no spill.
__global__ __launch_bounds__(512, 2) void k_attn(
    const u16* __restrict__ qp, const u16* __restrict__ kp,
    const u16* __restrict__ vnT, u16* __restrict__ ao)
{
  __shared__ alignas(128) unsigned char sm[65536];   // 2 x (K 16KB + V 16KB); reused by reduce
  __shared__ float p4s[2][256];
  char* smc = (char*)sm;
  int tid = threadIdx.x, lane = tid&63, wv = tid>>6;
  int l31 = lane&31, hi = lane>>5;
  int qi = wv>>2, kj = wv&3;
  int L = blockIdx.x;
  int xcd = L&7, iw = L>>3;            // iw 0..63
  int bh = xcd*4 + (iw>>4);            // consecutive iw share bh (L1/L2 reuse)
  int qx = iw&15;
  int qb = qx*128;
  int b = bh>>4, h = bh&15;
  const u16* Kb = kp  + (size_t)bh*S_*HD_;
  const u16* Vb = vnT + (size_t)bh*HD_*S_;
  const u16* Qb = qp  + (size_t)bh*S_*HD_;
  int q0 = qb + qi*64;

  // Q fragments (B-operand): 2 q-frags of 32 rows each
  bf16x8 qf[2][4];
  #pragma unroll
  for (int f=0;f<2;++f)
    #pragma unroll
    for (int kk=0;kk<4;++kk)
      qf[f][kk] = *reinterpret_cast<const bf16x8*>(Qb + (size_t)(q0 + f*32 + l31)*HD_ + kk*16 + hi*8);

  f32x16 z16 = {};
  f32x16 o[2][2];
  #pragma unroll
  for (int f=0;f<2;++f){ o[f][0] = z16; o[f][1] = z16; }
  f32x2 p4a[2] = {{0.f,0.f},{0.f,0.f}};

  // staging sources (pre-swizzled cols). K tile [128][128B]; V tile [64][256B].
  // 8 waves x 4 gl_lds x 1KB = 32KB per tile buffer.
  const char* kSrcC[2]; const char* vSrcC[2];
  #pragma unroll
  for (int c=0;c<2;++c){
    int off = wv*2048 + c*1024 + lane*16;
    int rk = off>>7, ck = off&127;
    kSrcC[c] = (const char*)Kb + (size_t)rk*128 + (ck ^ ((rk&7)<<4));
    int rv = off>>8, cv = off&255;
    vSrcC[c] = (const char*)Vb + (size_t)rv*4096 + (cv ^ ((rv&15)<<4));
  }

  auto STAGE = [&](int bsel, int kt){
    char* db = smc + bsel*32768 + wv*2048;
    #pragma unroll
    for (int c=0;c<2;++c) gl_lds16(kSrcC[c] + (size_t)kt*16384, db + c*1024);
    #pragma unroll
    for (int c=0;c<2;++c) gl_lds16(vSrcC[c] + (size_t)kt*256,   db + 16384 + c*1024);
  };

  auto PACK = [&](const f32x16& e, u32 (&w)[4][2], f32x2& pa){
    #pragma unroll
    for (int j=0;j<8;++j){
      const int g=j>>1, i=j&1;
      float a = e[4*g+2*i], c = e[4*g+2*i+1];
      f32x2 pr = {a, c};
      f32x2 e2;
      asm("v_pk_mul_f32 %0, %1, %1" : "=v"(e2) : "v"(pr));
      asm("v_pk_fma_f32 %0, %1, %1, %0" : "+v"(pa) : "v"(e2));
      w[g][i] = cvt_pk_bf16(a, c);
    }
  };
  auto AFRAG = [&](u32 (&w)[4][2], int s) -> bf16x8 {
    u32 a0 = w[2*s][0], b0 = w[2*s+1][0];
    u32 a1 = w[2*s][1], b1 = w[2*s+1][1];
    asm("v_permlane32_swap_b32 %0, %1" : "+v"(a0), "+v"(b0));
    asm("v_permlane32_swap_b32 %0, %1" : "+v"(a1), "+v"(b1));
    u32x4 fw = {a0, a1, b0, b1};
    return __builtin_bit_cast(bf16x8, fw);
  };

  const int NT = S_/128;   // 16
  STAGE(0, 0); STAGE(1, 1);

  u32 w0[4][2], w1[4][2];

  #pragma unroll 1
  for (int t=0; t<NT; ++t){
    if (t < NT-1) { asm volatile("s_waitcnt vmcnt(4)" ::: "memory"); }
    else          { asm volatile("s_waitcnt vmcnt(0)" ::: "memory"); }
    __builtin_amdgcn_s_barrier();
    asm volatile("" ::: "memory");
    const unsigned char* K_ = sm + (t&1)*32768;
    const unsigned char* V_ = K_ + 16384;

    // QK^T: wave's 32-key quarter (keys kj*32..+31 of this tile)
    bf16x8 ka[4];
    #pragma unroll
    for (int kk=0;kk<4;++kk) ka[kk] = ldfrag(K_, kj*32 + l31, kk*32 + hi*16);
    f32x16 e0 = z16, e1 = z16;
    __builtin_amdgcn_s_setprio(1);
    #pragma unroll
    for (int kk=0;kk<4;++kk){
      e0 = __builtin_amdgcn_mfma_f32_32x32x16_bf16(ka[kk], qf[0][kk], e0, 0,0,0);
      e1 = __builtin_amdgcn_mfma_f32_32x32x16_bf16(ka[kk], qf[1][kk], e1, 0,0,0);
    }
    __builtin_amdgcn_s_setprio(0);

    PACK(e0, w0, p4a[0]);
    PACK(e1, w1, p4a[1]);

    // PV over the same 32-key quarter: byte cols kj*64 .. +63 of V tile
    bf16x8 vb[2][2];
    #pragma unroll
    for (int s=0;s<2;++s){
      vb[s][0] = ldfragV(V_, l31,    kj*64 + s*32 + hi*16);
      vb[s][1] = ldfragV(V_, 32+l31, kj*64 + s*32 + hi*16);
    }
    __builtin_amdgcn_s_setprio(1);
    #pragma unroll
    for (int s=0;s<2;++s){
      bf16x8 ef0 = AFRAG(w0, s);
      bf16x8 ef1 = AFRAG(w1, s);
      o[0][0] = __builtin_amdgcn_mfma_f32_32x32x16_bf16(ef0, vb[s][0], o[0][0], 0,0,0);
      o[0][1] = __builtin_amdgcn_mfma_f32_32x32x16_bf16(ef0, vb[s][1], o[0][1], 0,0,0);
      o[1][0] = __builtin_amdgcn_mfma_f32_32x32x16_bf16(ef1, vb[s][0], o[1][0], 0,0,0);
      o[1][1] = __builtin_amdgcn_mfma_f32_32x32x16_bf16(ef1, vb[s][1], o[1][1], 0,0,0);
    }
    __builtin_amdgcn_s_setprio(0);

    asm volatile("" ::: "memory");
    __builtin_amdgcn_s_barrier();      // everyone done reading buf[t&1]
    asm volatile("" ::: "memory");
    if (t+2 < NT) STAGE(t&1, t+2);
  }

  // ---- 3-stage cross-wave (4 kj) reduce via LDS, then L4 scale + store ----
  float p4f[2];
  #pragma unroll
  for (int f=0;f<2;++f) p4f[f] = p4a[f].x + p4a[f].y;

  auto writeO = [&](int sl){
    float* base = (float*)(smc + sl*32768);
    #pragma unroll
    for (int f=0;f<2;++f){
      #pragma unroll
      for (int ds=0;ds<2;++ds){
        float* dst = base + ((((qi*2+f)*2+ds)*64 + lane)*16);
        #pragma unroll
        for (int r4=0;r4<4;++r4)
          *(float4*)(dst + r4*4) = make_float4(o[f][ds][r4*4],o[f][ds][r4*4+1],o[f][ds][r4*4+2],o[f][ds][r4*4+3]);
      }
      p4s[sl][(qi*2+f)*64 + lane] = p4f[f];
    }
  };
  auto accO = [&](int sl){
    const float* base = (const float*)(smc + sl*32768);
    #pragma unroll
    for (int f=0;f<2;++f){
      #pragma unroll
      for (int ds=0;ds<2;++ds){
        const float* srcp = base + ((((qi*2+f)*2+ds)*64 + lane)*16);
        #pragma unroll
        for (int r4=0;r4<4;++r4){
          float4 t = *(const float4*)(srcp + r4*4);
          o[f][ds][r4*4]+=t.x; o[f][ds][r4*4+1]+=t.y; o[f][ds][r4*4+2]+=t.z; o[f][ds][r4*4+3]+=t.w;
        }
      }
      p4f[f] += p4s[sl][(qi*2+f)*64 + lane];
    }
  };

  __syncthreads();                      // main-loop LDS reads complete
  if (kj==1) writeO(0);
  if (kj==3) writeO(1);
  __syncthreads();
  if (kj==0) accO(0);
  if (kj==2) accO(1);
  __syncthreads();
  if (kj==2) writeO(0);
  __syncthreads();
  if (kj==0){
    accO(0);
    #pragma unroll
    for (int f=0;f<2;++f) p4f[f] += __shfl_xor(p4f[f], 32);
    float sc0 = GAMMA * rsqrtf(sqrtf(p4f[0]));
    float sc1 = GAMMA * rsqrtf(sqrtf(p4f[1]));
    #pragma unroll
    for (int f=0;f<2;++f){
      #pragma unroll
      for (int r=0;r<16;++r){
        int qrow = (r&3) + 8*(r>>2) + 4*hi;
        float scr = __shfl(f==0 ? sc0 : sc1, qrow);
        size_t n = (size_t)b*S_ + q0 + f*32 + qrow;
        u16* dst = ao + n*E_ + h*HD_;
        dst[l31]    = f2bf(o[f][0][r] * scr);
        dst[32+l31] = f2bf(o[f][1][r] * scr);
      }
    }
  }
}

// ---------------- K3/K5: 128x64-tile bf16 GEMM (y = A @ Bw^T), T3/T4 pipeline ----------------
template<int MODE>
__global__ __launch_bounds__(256, 2) void k_gemm(
    const u16* __restrict__ A, const u16* __restrict__ Bw,
    const float* __restrict__ bias, const float* __restrict__ auxf,
    const u16* __restrict__ aux16, float* __restrict__ out32, u16* __restrict__ out16)
{
  __shared__ alignas(128) unsigned char sm[73728];   // 3 x (A 16KB + B 8KB)
  char* smc = (char*)sm;
  int tid = threadIdx.x, lane = tid&63, wv = tid>>6;
  int l31 = lane&31, hi = lane>>5;
  int wr = wv>>1, wc = wv&1;
  int LL = (blockIdx.x & 7)*64 + (blockIdx.x >> 3);   // 512 = 8 XCD x 64
  int mt = LL >> 4, nt = LL & 15;
  int m0 = mt*128, n0 = nt*64;

  int ric  = lane>>3;
  int colb = ((lane&7)*16) ^ ((ric&7)<<4);
  const char* aSrc[4]; const char* bSrc[2];
  #pragma unroll
  for (int j=0;j<4;++j)
    aSrc[j] = (const char*)A  + ((size_t)(m0 + wv*32 + 8*j + ric)*E_)*2 + colb;
  #pragma unroll
  for (int j=0;j<2;++j)
    bSrc[j] = (const char*)Bw + ((size_t)(n0 + wv*16 + 8*j + ric)*E_)*2 + colb;

  auto STAGE = [&](int bsel, int t){
    char* db = smc + bsel*24576;
    size_t kb2 = (size_t)t*128;
    #pragma unroll
    for (int j=0;j<4;++j) gl_lds16(aSrc[j] + kb2, db + (wv*4+j)*1024);
    #pragma unroll
    for (int j=0;j<2;++j) gl_lds16(bSrc[j] + kb2, db + 16384 + (wv*2+j)*1024);
  };

  f32x16 acc[2] = {{}, {}};

  const int NK = E_/64;   // 16
  STAGE(0, 0); STAGE(1, 1);

  #pragma unroll 1
  for (int t=0; t<NK; ++t){
    if (t < NK-1) { asm volatile("s_waitcnt vmcnt(6)" ::: "memory"); }
    else          { asm volatile("s_waitcnt vmcnt(0)" ::: "memory"); }
    __builtin_amdgcn_s_barrier();
    asm volatile("" ::: "memory");
    if (t+2 < NK) STAGE((t+2)%3, t+2);

    const unsigned char* Ap_ = sm + (t%3)*24576;
    const unsigned char* Bp_ = Ap_ + 16384;
    #pragma unroll
    for (int kk=0;kk<4;++kk){
      bf16x8 bfr = ldfrag(Bp_, wc*32 + l31, kk*32 + hi*16);
      bf16x8 af0 = ldfrag(Ap_, wr*64 + l31,      kk*32 + hi*16);
      bf16x8 af1 = ldfrag(Ap_, wr*64 + 32 + l31, kk*32 + hi*16);
      __builtin_amdgcn_s_setprio(1);
      acc[0] = __builtin_amdgcn_mfma_f32_32x32x16_bf16(af0, bfr, acc[0], 0,0,0);
      acc[1] = __builtin_amdgcn_mfma_f32_32x32x16_bf16(af1, bfr, acc[1], 0,0,0);
      __builtin_amdgcn_s_setprio(0);
    }
  }

  int col = n0 + wc*32 + l31;
  float bi = bias[col];
  #pragma unroll
  for (int rg=0;rg<2;++rg)
    #pragma unroll
    for (int r=0;r<16;++r){
      int mrow = m0 + wr*64 + rg*32 + (r&3) + 8*(r>>2) + 4*hi;
      size_t idx = (size_t)mrow*E_ + col;
      float v = acc[rg][r] + bi;
      if (MODE == 0){
        out16[idx] = f2bf(v + auxf[idx]);
      } else {
        float gg = 1.f/(1.f + __expf(-v));
        out32[idx] = bf2f(aux16[idx]) * gg;
      }
    }
}

// ---------------- K4: LayerNorm over embed dim; bf16 in -> bf16 out ----------------
__global__ __launch_bounds__(256) void k_ln(
    const u16* __restrict__ xin, const float* __restrict__ lnw, const float* __restrict__ lnb,
    u16* __restrict__ xout)
{
  __shared__ float red[8];
  __shared__ float stats[2];
  int row = blockIdx.x, tid = threadIdx.x;
  ushort4 xr = reinterpret_cast<const ushort4*>(xin + (size_t)row*E_)[tid];
  float x0 = bf2f(xr.x), x1 = bf2f(xr.y), x2 = bf2f(xr.z), x3 = bf2f(xr.w);
  float s  = x0 + x1 + x2 + x3;
  float s2 = x0*x0 + x1*x1 + x2*x2 + x3*x3;
  #pragma unroll
  for (int m=1;m<64;m<<=1){ s += __shfl_xor(s,m); s2 += __shfl_xor(s2,m); }
  if ((tid&63)==0){ red[tid>>6] = s; red[4+(tid>>6)] = s2; }
  __syncthreads();
  if (tid==0){
    float ts  = red[0]+red[1]+red[2]+red[3];
    float ts2 = red[4]+red[5]+red[6]+red[7];
    float mu  = ts * (1.f/E_);
    float var = ts2 * (1.f/E_) - mu*mu;
    stats[0] = mu; stats[1] = rsqrtf(var + 1e-5f);
  }
  __syncthreads();
  float mu = stats[0], rstd = stats[1];
  float4 w  = reinterpret_cast<const float4*>(lnw)[tid];
  float4 bb = reinterpret_cast<const float4*>(lnb)[tid];
  ushort4 p;
  p.x = f2bf((x0-mu)*rstd*w.x + bb.x);
  p.y = f2bf((x1-mu)*rstd*w.y + bb.y);
  p.z = f2bf((x2-mu)*rstd*w.z + bb.z);
  p.w = f2bf((x3-mu)*rstd*w.w + bb.w);
  reinterpret_cast<ushort4*>(xout + (size_t)row*E_)[tid] = p;
}

// ---------------- host launch ----------------
extern "C" void kernel_launch(void* const* d_in, const int* in_sizes, int n_in,
                              void* d_out, int out_size, void* d_ws, size_t ws_size,
                              hipStream_t stream)
{
  const float* value = (const float*)d_in[0];
  const float* key   = (const float*)d_in[1];
  const float* query = (const float*)d_in[2];
  const float* Wq    = (const float*)d_in[3];
  const float* Wk    = (const float*)d_in[4];
  const float* Wv    = (const float*)d_in[5];
  const float* Wo    = (const float*)d_in[6];
  const float* bo    = (const float*)d_in[7];
  const float* lnw   = (const float*)d_in[8];
  const float* lnb   = (const float*)d_in[9];
  const float* Wsq   = (const float*)d_in[10];
  const float* bsq   = (const float*)d_in[11];
  float* out = (float*)d_out;

  char* ws = (char*)d_ws;
  const size_t MB = 1ull<<20;
  u16*   qp     = (u16*)(ws + 0*MB);    // K1->K2
  u16*   kp     = (u16*)(ws + 8*MB);    // K1->K2
  u16*   vnT    = (u16*)(ws + 16*MB);   // K1->K2
  u16*   ao     = (u16*)(ws + 24*MB);   // K2->K3 (8MB)
  u16*   xres16 = (u16*)(ws + 8*MB);    // K3->K4 (8MB, over kp)
  u16*   x16    = (u16*)(ws + 16*MB);   // K4->K5 (8MB, over vnT)
  u16*   wo16   = (u16*)(ws + 48*MB);
  u16*   wsq16  = (u16*)(ws + 50*MB);

  k_proj<<<dim3(N_/64, H_+2), 256, 0, stream>>>(query, key, value, Wq, Wk, Wv,
                                                qp, kp, vnT, Wo, Wsq, wo16, wsq16);
  k_attn<<<512, 512, 0, stream>>>(qp, kp, vnT, ao);
  k_gemm<0><<<512, 256, 0, stream>>>(ao, wo16, bo, query, (const u16*)nullptr, (float*)nullptr, xres16);
  k_ln  <<<N_, 256, 0, stream>>>(xres16, lnw, lnb, x16);
  k_gemm<1><<<512, 256, 0, stream>>>(x16, wsq16, bsq, (const float*)nullptr, x16, out, (u16*)nullptr);
}

// Round 12
// 108.806 us; speedup vs baseline: 1.6037x; 1.1306x over previous
//
#include <hip/hip_runtime.h>
#include <stdint.h>

#define B_ 2
#define S_ 2048
#define E_ 1024
#define H_ 16
#define HD_ 64
#define N_ (B_*S_)
#define BH_ (B_*H_)
#define GAMMA 0.01f

typedef __attribute__((ext_vector_type(8))) short bf16x8;
typedef __attribute__((ext_vector_type(4))) float f32x4;
typedef __attribute__((ext_vector_type(2))) float f32x2;
typedef __attribute__((ext_vector_type(16))) float f32x16;
typedef __attribute__((ext_vector_type(4))) unsigned int u32x4;
typedef unsigned short u16;
typedef unsigned int u32;

// byte-level XOR swizzle within a 128B row
#define SWZ(row, kb) ((kb) ^ (((row)&7)<<4))

__device__ __forceinline__ u16 f2bf(float f){
  union { float f; u32 u; } v; v.f = f;
  return (u16)((v.u + 0x7FFFu + ((v.u>>16)&1u)) >> 16);
}

__device__ __forceinline__ float bf2f(u16 u){
  union { u32 u; float f; } v; v.u = ((u32)u)<<16; return v.f;
}

__device__ __forceinline__ u32 cvt_pk_bf16(float lo, float hi){
  u32 r; asm("v_cvt_pk_bf16_f32 %0, %1, %2" : "=v"(r) : "v"(lo), "v"(hi)); return r;
}

__device__ __forceinline__ uint4 pack8(float4 a, float4 b){
  uint4 r;
  r.x = (u32)f2bf(a.x) | ((u32)f2bf(a.y)<<16);
  r.y = (u32)f2bf(a.z) | ((u32)f2bf(a.w)<<16);
  r.z = (u32)f2bf(b.x) | ((u32)f2bf(b.y)<<16);
  r.w = (u32)f2bf(b.z) | ((u32)f2bf(b.w)<<16);
  return r;
}

__device__ __forceinline__ bf16x8 ldfrag(const unsigned char* base, int row, int kbyte){
  return *reinterpret_cast<const bf16x8*>(base + row*128 + SWZ(row, kbyte));
}
// V tile has 256B rows; 16-slot swizzle
__device__ __forceinline__ bf16x8 ldfragV(const unsigned char* base, int row, int col){
  return *reinterpret_cast<const bf16x8*>(base + row*256 + (col ^ ((row&15)<<4)));
}

// async global->LDS, 16B/lane; LDS dest = wave-uniform base + lane*16 (linear),
// swizzling achieved by permuting the per-lane SOURCE address
__device__ __forceinline__ void gl_lds16(const void* g, void* l){
  __builtin_amdgcn_global_load_lds(
      (const __attribute__((address_space(1))) unsigned int*)g,
      (__attribute__((address_space(3))) unsigned int*)l, 16, 0, 0);
}

// ---------------- K1: per-head QKV projection + xnorm(v), V transposed ----------------
// blockIdx.y >= H_: weight-conversion slabs (folded former k_cvt)
__device__ __forceinline__ void proj_mfma(const unsigned char* X, const unsigned char* W,
                                          int wid, int l15, int g4, f32x4 acc[4])
{
  f32x4 z = {0.f,0.f,0.f,0.f};
  acc[0]=z; acc[1]=z; acc[2]=z; acc[3]=z;
  #pragma unroll
  for (int kk=0;kk<2;++kk){
    int kbyte = kk*64 + g4*16;
    bf16x8 a = ldfrag(X, wid*16 + l15, kbyte);
    #pragma unroll
    for (int t=0;t<4;++t){
      bf16x8 w = ldfrag(W, t*16 + l15, kbyte);
      acc[t] = __builtin_amdgcn_mfma_f32_16x16x32_bf16(a, w, acc[t], 0, 0, 0);
    }
  }
}

__global__ __launch_bounds__(256) void k_proj(
    const float* __restrict__ qin, const float* __restrict__ kin, const float* __restrict__ vin,
    const float* __restrict__ Wq, const float* __restrict__ Wk, const float* __restrict__ Wv,
    u16* __restrict__ qp, u16* __restrict__ kp, u16* __restrict__ vnT,
    const float* __restrict__ Wo, const float* __restrict__ Wsq,
    u16* __restrict__ wo16, u16* __restrict__ wsq16)
{
  __shared__ alignas(16) unsigned char sm[57344];
  if (blockIdx.y >= H_){
    int cblk = (blockIdx.y - H_)*64 + blockIdx.x;
    int n4 = (E_*E_)/4;
    for (int i = cblk*256 + threadIdx.x; i < 2*n4; i += 128*256){
      const float4* src; ushort4* dst; int j;
      if (i < n4){ src=(const float4*)Wo;  dst=(ushort4*)wo16;  j=i; }
      else       { src=(const float4*)Wsq; dst=(ushort4*)wsq16; j=i-n4; }
      float4 v = src[j];
      ushort4 p; p.x=f2bf(v.x); p.y=f2bf(v.y); p.z=f2bf(v.z); p.w=f2bf(v.w);
      dst[j] = p;
    }
    return;
  }
  const int XQ=0, XK=8192, XV=16384, WQS=24576, WKS=32768, WVS=40960, VT=49152;
  int tid = threadIdx.x, lane = tid&63, wid = tid>>6;
  int l15 = lane&15, g4 = lane>>4;
  int tb = blockIdx.x*64;
  int h  = blockIdx.y;
  int b  = tb >> 11;
  int sbase = tb & 2047;
  int bh = b*H_ + h;

  {
    int rl = tid>>2;
    int d0 = (tid&3)*16;
    const float* xs[3] = { qin, kin, vin };
    const float* wsrc[3] = { Wq, Wk, Wv };
    const int xoff[3] = {XQ,XK,XV}, woff[3] = {WQS,WKS,WVS};
    #pragma unroll
    for (int m3=0;m3<3;++m3){
      const float4* gx = reinterpret_cast<const float4*>(xs[m3] + (size_t)(tb+rl)*E_ + h*HD_ + d0);
      float4 a=gx[0], bb=gx[1], c=gx[2], d=gx[3];
      *(uint4*)(sm + xoff[m3] + rl*128 + SWZ(rl, d0*2))    = pack8(a,bb);
      *(uint4*)(sm + xoff[m3] + rl*128 + SWZ(rl, d0*2+16)) = pack8(c,d);
      const float4* gw = reinterpret_cast<const float4*>(wsrc[m3] + rl*64 + d0);
      float4 e=gw[0], f=gw[1], g2=gw[2], h2=gw[3];
      *(uint4*)(sm + woff[m3] + rl*128 + SWZ(rl, d0*2))    = pack8(e,f);
      *(uint4*)(sm + woff[m3] + rl*128 + SWZ(rl, d0*2+16)) = pack8(g2,h2);
    }
  }
  __syncthreads();

  f32x4 acc[4];
  proj_mfma(sm+XQ, sm+WQS, wid, l15, g4, acc);
  #pragma unroll
  for (int t=0;t<4;++t)
    #pragma unroll
    for (int r=0;r<4;++r){
      int tokl = wid*16 + g4*4 + r;
      qp[((size_t)bh*S_ + sbase + tokl)*HD_ + t*16 + l15] = f2bf(acc[t][r]);
    }
  proj_mfma(sm+XK, sm+WKS, wid, l15, g4, acc);
  #pragma unroll
  for (int t=0;t<4;++t)
    #pragma unroll
    for (int r=0;r<4;++r){
      int tokl = wid*16 + g4*4 + r;
      kp[((size_t)bh*S_ + sbase + tokl)*HD_ + t*16 + l15] = f2bf(acc[t][r]);
    }
  proj_mfma(sm+XV, sm+WVS, wid, l15, g4, acc);
  {
    float p4r[4] = {0.f,0.f,0.f,0.f};
    #pragma unroll
    for (int t=0;t<4;++t)
      #pragma unroll
      for (int r=0;r<4;++r){ float e = acc[t][r]; float e2 = e*e; p4r[r] += e2*e2; }
    #pragma unroll
    for (int r=0;r<4;++r){
      float p = p4r[r];
      p += __shfl_xor(p,1); p += __shfl_xor(p,2); p += __shfl_xor(p,4); p += __shfl_xor(p,8);
      p4r[r] = GAMMA / sqrtf(sqrtf(p));
    }
    #pragma unroll
    for (int t=0;t<4;++t)
      #pragma unroll
      for (int r=0;r<4;++r){
        int tokl = wid*16 + g4*4 + r;
        int dd = t*16 + l15;
        *(u16*)(sm + VT + dd*128 + SWZ(dd, tokl*2)) = f2bf(acc[t][r] * p4r[r]);
      }
  }
  __syncthreads();
  {
    int dd = tid>>2; int c2 = tid&3;
    size_t gbase = ((size_t)bh*HD_ + dd)*S_ + sbase + c2*16;
    uint4 v0 = *(const uint4*)(sm + VT + dd*128 + SWZ(dd, c2*32));
    uint4 v1 = *(const uint4*)(sm + VT + dd*128 + SWZ(dd, c2*32+16));
    *(uint4*)(vnT + gbase)     = v0;
    *(uint4*)(vnT + gbase + 8) = v1;
  }
}

// ---------------- K2: flash attention, KVBLK=128, Fq=2 (round-9 version, best known) ----------------
__global__ __launch_bounds__(256, 2) void k_attn(
    const u16* __restrict__ qp, const u16* __restrict__ kp,
    const u16* __restrict__ vnT, u16* __restrict__ ao)
{
  __shared__ alignas(128) unsigned char sm[65536];   // 2 x (K 16KB + V 16KB)
  char* smc = (char*)sm;
  int tid = threadIdx.x, lane = tid&63, wv = tid>>6;
  int l31 = lane&31, hi = lane>>5;
  int qi = wv>>1, kj = wv&1;
  int L = blockIdx.x;
  int xcd = L&7, iw = L>>3;            // iw 0..63
  int bh = xcd*4 + (iw>>4);            // consecutive iw share bh (L1/L2 reuse)
  int qx = iw&15;
  int qb = qx*128;
  int b = bh>>4, h = bh&15;
  const u16* Kb = kp  + (size_t)bh*S_*HD_;
  const u16* Vb = vnT + (size_t)bh*HD_*S_;
  const u16* Qb = qp  + (size_t)bh*S_*HD_;
  int q0 = qb + qi*64;

  bf16x8 qf[2][4];
  #pragma unroll
  for (int f=0;f<2;++f)
    #pragma unroll
    for (int kk=0;kk<4;++kk)
      qf[f][kk] = *reinterpret_cast<const bf16x8*>(Qb + (size_t)(q0 + f*32 + l31)*HD_ + kk*16 + hi*8);

  f32x16 z16 = {};
  f32x16 o[2][2];
  #pragma unroll
  for (int f=0;f<2;++f){ o[f][0] = z16; o[f][1] = z16; }
  f32x2 p4a[2] = {{0.f,0.f},{0.f,0.f}};
  f32x2 p4b[2] = {{0.f,0.f},{0.f,0.f}};

  const char* kSrcC[4]; const char* vSrcC[4];
  #pragma unroll
  for (int c=0;c<4;++c){
    int rk = wv*32 + c*8 + (lane>>3);
    int ck = ((lane&7)*16) ^ ((rk&7)<<4);
    kSrcC[c] = (const char*)Kb + (size_t)rk*128 + ck;
    int rv = wv*16 + c*4 + (lane>>4);
    int cv = ((lane&15)*16) ^ ((rv&15)<<4);
    vSrcC[c] = (const char*)Vb + (size_t)rv*4096 + cv;
  }

  auto STAGE = [&](int bsel, int kt){
    char* db = smc + bsel*32768 + wv*4096;
    #pragma unroll
    for (int c=0;c<4;++c) gl_lds16(kSrcC[c] + (size_t)kt*16384, db + c*1024);
    #pragma unroll
    for (int c=0;c<4;++c) gl_lds16(vSrcC[c] + (size_t)kt*256,   db + 16384 + c*1024);
  };

  auto PACK = [&](const f32x16& e, u32 (&w)[4][2], f32x2& pa){
    #pragma unroll
    for (int j=0;j<8;++j){
      const int g=j>>1, i=j&1;
      float a = e[4*g+2*i], c = e[4*g+2*i+1];
      f32x2 pr = {a, c};
      f32x2 e2;
      asm("v_pk_mul_f32 %0, %1, %1" : "=v"(e2) : "v"(pr));
      asm("v_pk_fma_f32 %0, %1, %1, %0" : "+v"(pa) : "v"(e2));
      w[g][i] = cvt_pk_bf16(a, c);
    }
  };
  auto AFRAG = [&](u32 (&w)[4][2], int s) -> bf16x8 {
    u32 a0 = w[2*s][0], b0 = w[2*s+1][0];
    u32 a1 = w[2*s][1], b1 = w[2*s+1][1];
    asm("v_permlane32_swap_b32 %0, %1" : "+v"(a0), "+v"(b0));
    asm("v_permlane32_swap_b32 %0, %1" : "+v"(a1), "+v"(b1));
    u32x4 fw = {a0, a1, b0, b1};
    return __builtin_bit_cast(bf16x8, fw);
  };

  auto QK = [&](const unsigned char* K_, int s2, f32x16& E0, f32x16& E1){
    bf16x8 ka[4];
    #pragma unroll
    for (int kk=0;kk<4;++kk) ka[kk] = ldfrag(K_, kj*64 + s2*32 + l31, kk*32 + hi*16);
    E0 = z16; E1 = z16;
    __builtin_amdgcn_s_setprio(1);
    #pragma unroll
    for (int kk=0;kk<4;++kk){
      E0 = __builtin_amdgcn_mfma_f32_32x32x16_bf16(ka[kk], qf[0][kk], E0, 0,0,0);
      E1 = __builtin_amdgcn_mfma_f32_32x32x16_bf16(ka[kk], qf[1][kk], E1, 0,0,0);
    }
    __builtin_amdgcn_s_setprio(0);
  };

  auto PVF = [&](const unsigned char* V_, int s2, u32 (&w0)[4][2], u32 (&w1)[4][2]){
    bf16x8 vb[2][2];
    #pragma unroll
    for (int s=0;s<2;++s){
      vb[s][0] = ldfragV(V_, l31,    kj*128 + s2*64 + s*32 + hi*16);
      vb[s][1] = ldfragV(V_, 32+l31, kj*128 + s2*64 + s*32 + hi*16);
    }
    __builtin_amdgcn_s_setprio(1);
    #pragma unroll
    for (int s=0;s<2;++s){
      bf16x8 ef0 = AFRAG(w0, s);
      bf16x8 ef1 = AFRAG(w1, s);
      o[0][0] = __builtin_amdgcn_mfma_f32_32x32x16_bf16(ef0, vb[s][0], o[0][0], 0,0,0);
      o[0][1] = __builtin_amdgcn_mfma_f32_32x32x16_bf16(ef0, vb[s][1], o[0][1], 0,0,0);
      o[1][0] = __builtin_amdgcn_mfma_f32_32x32x16_bf16(ef1, vb[s][0], o[1][0], 0,0,0);
      o[1][1] = __builtin_amdgcn_mfma_f32_32x32x16_bf16(ef1, vb[s][1], o[1][1], 0,0,0);
    }
    __builtin_amdgcn_s_setprio(0);
  };

  const int NT = S_/128;   // 16
  STAGE(0, 0); STAGE(1, 1);

  f32x16 eA0, eA1, eB0, eB1;
  u32 wA0[4][2], wA1[4][2], wB0[4][2], wB1[4][2];

  #pragma unroll 1
  for (int t=0; t<NT; ++t){
    if (t < NT-1) { asm volatile("s_waitcnt vmcnt(8)" ::: "memory"); }
    else          { asm volatile("s_waitcnt vmcnt(0)" ::: "memory"); }
    __builtin_amdgcn_s_barrier();
    asm volatile("" ::: "memory");
    const unsigned char* K_ = sm + (t&1)*32768;
    const unsigned char* V_ = K_ + 16384;

    QK(K_, 0, eA0, eA1);
    QK(K_, 1, eB0, eB1);
    PACK(eA0, wA0, p4a[0]);
    PACK(eA1, wA1, p4a[1]);
    PVF(V_, 0, wA0, wA1);
    PACK(eB0, wB0, p4b[0]);
    PACK(eB1, wB1, p4b[1]);
    PVF(V_, 1, wB0, wB1);

    asm volatile("" ::: "memory");
    __builtin_amdgcn_s_barrier();
    asm volatile("" ::: "memory");
    if (t+2 < NT) STAGE(t&1, t+2);
  }

  float p4f[2];
  #pragma unroll
  for (int f=0;f<2;++f) p4f[f] = p4a[f].x + p4a[f].y + p4b[f].x + p4b[f].y;

  __syncthreads();
  float* red  = (float*)smc;
  float* redp = (float*)(smc + 32768);
  if (kj==1){
    #pragma unroll
    for (int f=0;f<2;++f){
      #pragma unroll
      for (int ds=0;ds<2;++ds){
        float* dst = red + ((((qi*2+f)*2+ds)*64 + lane)*16);
        #pragma unroll
        for (int r4=0;r4<4;++r4)
          *(float4*)(dst + r4*4) = make_float4(o[f][ds][r4*4],o[f][ds][r4*4+1],o[f][ds][r4*4+2],o[f][ds][r4*4+3]);
      }
      redp[(qi*2+f)*64 + lane] = p4f[f];
    }
  }
  __syncthreads();
  if (kj==0){
    #pragma unroll
    for (int f=0;f<2;++f){
      #pragma unroll
      for (int ds=0;ds<2;++ds){
        const float* srcp = red + ((((qi*2+f)*2+ds)*64 + lane)*16);
        #pragma unroll
        for (int r4=0;r4<4;++r4){
          float4 t = *(const float4*)(srcp + r4*4);
          o[f][ds][r4*4]+=t.x; o[f][ds][r4*4+1]+=t.y; o[f][ds][r4*4+2]+=t.z; o[f][ds][r4*4+3]+=t.w;
        }
      }
      p4f[f] += redp[(qi*2+f)*64 + lane];
      p4f[f] += __shfl_xor(p4f[f], 32);
    }
    float sc0 = GAMMA * rsqrtf(sqrtf(p4f[0]));
    float sc1 = GAMMA * rsqrtf(sqrtf(p4f[1]));
    #pragma unroll
    for (int f=0;f<2;++f){
      #pragma unroll
      for (int r=0;r<16;++r){
        int qrow = (r&3) + 8*(r>>2) + 4*hi;
        float scr = __shfl(f==0 ? sc0 : sc1, qrow);
        size_t n = (size_t)b*S_ + q0 + f*32 + qrow;
        u16* dst = ao + n*E_ + h*HD_;
        dst[l31]    = f2bf(o[f][0][r] * scr);
        dst[32+l31] = f2bf(o[f][1][r] * scr);
      }
    }
  }
}

// ---------------- K3/K5: 128x128-tile bf16 GEMM, 64x64 per wave (1:1 MFMA:ds_read) ----------------
// BM=BN=128, BK=64; grid 256; 4 waves = 2wr x 2wc, each wave 64x64 output via
// acc[2][2] f32x16. Per kk: 4 ds_read -> 4 MFMA (vs old 3:2). 2 x 32KB LDS dbuf,
// one barrier pair + counted vmcnt(8)/K-step. XCD swizzle: 4 m-panels per XCD.
// MODE 0: out16[idx] = bf16(acc + bias[col] + auxf[idx])            (Wo proj + residual)
// MODE 1: out32[idx] = bf2f(aux16[idx]) * sigmoid(acc + bias[col])  (SE gate)
template<int MODE>
__global__ __launch_bounds__(256, 2) void k_gemm(
    const u16* __restrict__ A, const u16* __restrict__ Bw,
    const float* __restrict__ bias, const float* __restrict__ auxf,
    const u16* __restrict__ aux16, float* __restrict__ out32, u16* __restrict__ out16)
{
  __shared__ alignas(128) unsigned char sm[65536];   // 2 x (A 16KB + B 16KB)
  char* smc = (char*)sm;
  int tid = threadIdx.x, lane = tid&63, wv = tid>>6;
  int l31 = lane&31, hi = lane>>5;
  int wr = wv>>1, wc = wv&1;
  // XCD swizzle: 256 = 8 XCD x 32; each XCD owns 4 contiguous m-panels x all 8 n
  int LL = (blockIdx.x & 7)*32 + (blockIdx.x >> 3);
  int mt = LL >> 3, nt = LL & 7;                      // 32 m-tiles x 8 n-tiles
  int m0 = mt*128, n0 = nt*128;

  // staging sources (pre-swizzled col within 128B row); wave wv stages rows wv*32..+31
  const char* aS[4]; const char* bS[4];
  #pragma unroll
  for (int c=0;c<4;++c){
    int off = wv*4096 + c*1024 + lane*16;
    int r = off>>7, cl = off&127;
    int cs = cl ^ ((r&7)<<4);
    aS[c] = (const char*)A  + ((size_t)(m0+r)*E_)*2 + cs;
    bS[c] = (const char*)Bw + ((size_t)(n0+r)*E_)*2 + cs;
  }

  auto STAGE = [&](int bsel, int t){
    char* db = smc + bsel*32768 + wv*4096;
    size_t kb2 = (size_t)t*128;                        // 64 k * 2B
    #pragma unroll
    for (int c=0;c<4;++c) gl_lds16(aS[c] + kb2, db + c*1024);
    #pragma unroll
    for (int c=0;c<4;++c) gl_lds16(bS[c] + kb2, db + 16384 + c*1024);
  };

  f32x16 acc[2][2] = {{{}, {}}, {{}, {}}};

  const int NK = E_/64;   // 16
  STAGE(0, 0); STAGE(1, 1);

  #pragma unroll 1
  for (int t=0; t<NK; ++t){
    if (t < NK-1) { asm volatile("s_waitcnt vmcnt(8)" ::: "memory"); }
    else          { asm volatile("s_waitcnt vmcnt(0)" ::: "memory"); }
    __builtin_amdgcn_s_barrier();
    asm volatile("" ::: "memory");

    const unsigned char* Ap_ = sm + (t&1)*32768;
    const unsigned char* Bp_ = Ap_ + 16384;
    #pragma unroll
    for (int kk=0;kk<4;++kk){
      int kbyte = kk*32 + hi*16;
      bf16x8 a0 = ldfrag(Ap_, wr*64 + l31,      kbyte);
      bf16x8 a1 = ldfrag(Ap_, wr*64 + 32 + l31, kbyte);
      bf16x8 b0 = ldfrag(Bp_, wc*64 + l31,      kbyte);
      bf16x8 b1 = ldfrag(Bp_, wc*64 + 32 + l31, kbyte);
      __builtin_amdgcn_s_setprio(1);
      acc[0][0] = __builtin_amdgcn_mfma_f32_32x32x16_bf16(a0, b0, acc[0][0], 0,0,0);
      acc[0][1] = __builtin_amdgcn_mfma_f32_32x32x16_bf16(a0, b1, acc[0][1], 0,0,0);
      acc[1][0] = __builtin_amdgcn_mfma_f32_32x32x16_bf16(a1, b0, acc[1][0], 0,0,0);
      acc[1][1] = __builtin_amdgcn_mfma_f32_32x32x16_bf16(a1, b1, acc[1][1], 0,0,0);
      __builtin_amdgcn_s_setprio(0);
    }

    asm volatile("" ::: "memory");
    __builtin_amdgcn_s_barrier();
    asm volatile("" ::: "memory");
    if (t+2 < NK) STAGE(t&1, t+2);
  }

  // epilogue: lane holds D[col = n0+wc*64+cg*32+l31][m = m0+wr*64+rg*32+crow(r,hi)]
  #pragma unroll
  for (int cg=0;cg<2;++cg){
    int col = n0 + wc*64 + cg*32 + l31;
    float bi = bias[col];
    #pragma unroll
    for (int rg=0;rg<2;++rg)
      #pragma unroll
      for (int r=0;r<16;++r){
        int mrow = m0 + wr*64 + rg*32 + (r&3) + 8*(r>>2) + 4*hi;
        size_t idx = (size_t)mrow*E_ + col;
        float v = acc[rg][cg][r] + bi;
        if (MODE == 0){
          out16[idx] = f2bf(v + auxf[idx]);
        } else {
          float gg = 1.f/(1.f + __expf(-v));
          out32[idx] = bf2f(aux16[idx]) * gg;
        }
      }
  }
}

// ---------------- K4: LayerNorm over embed dim; bf16 in -> bf16 out ----------------
__global__ __launch_bounds__(256) void k_ln(
    const u16* __restrict__ xin, const float* __restrict__ lnw, const float* __restrict__ lnb,
    u16* __restrict__ xout)
{
  __shared__ float red[8];
  __shared__ float stats[2];
  int row = blockIdx.x, tid = threadIdx.x;
  ushort4 xr = reinterpret_cast<const ushort4*>(xin + (size_t)row*E_)[tid];
  float x0 = bf2f(xr.x), x1 = bf2f(xr.y), x2 = bf2f(xr.z), x3 = bf2f(xr.w);
  float s  = x0 + x1 + x2 + x3;
  float s2 = x0*x0 + x1*x1 + x2*x2 + x3*x3;
  #pragma unroll
  for (int m=1;m<64;m<<=1){ s += __shfl_xor(s,m); s2 += __shfl_xor(s2,m); }
  if ((tid&63)==0){ red[tid>>6] = s; red[4+(tid>>6)] = s2; }
  __syncthreads();
  if (tid==0){
    float ts  = red[0]+red[1]+red[2]+red[3];
    float ts2 = red[4]+red[5]+red[6]+red[7];
    float mu  = ts * (1.f/E_);
    float var = ts2 * (1.f/E_) - mu*mu;
    stats[0] = mu; stats[1] = rsqrtf(var + 1e-5f);
  }
  __syncthreads();
  float mu = stats[0], rstd = stats[1];
  float4 w  = reinterpret_cast<const float4*>(lnw)[tid];
  float4 bb = reinterpret_cast<const float4*>(lnb)[tid];
  ushort4 p;
  p.x = f2bf((x0-mu)*rstd*w.x + bb.x);
  p.y = f2bf((x1-mu)*rstd*w.y + bb.y);
  p.z = f2bf((x2-mu)*rstd*w.z + bb.z);
  p.w = f2bf((x3-mu)*rstd*w.w + bb.w);
  reinterpret_cast<ushort4*>(xout + (size_t)row*E_)[tid] = p;
}

// ---------------- host launch ----------------
extern "C" void kernel_launch(void* const* d_in, const int* in_sizes, int n_in,
                              void* d_out, int out_size, void* d_ws, size_t ws_size,
                              hipStream_t stream)
{
  const float* value = (const float*)d_in[0];
  const float* key   = (const float*)d_in[1];
  const float* query = (const float*)d_in[2];
  const float* Wq    = (const float*)d_in[3];
  const float* Wk    = (const float*)d_in[4];
  const float* Wv    = (const float*)d_in[5];
  const float* Wo    = (const float*)d_in[6];
  const float* bo    = (const float*)d_in[7];
  const float* lnw   = (const float*)d_in[8];
  const float* lnb   = (const float*)d_in[9];
  const float* Wsq   = (const float*)d_in[10];
  const float* bsq   = (const float*)d_in[11];
  float* out = (float*)d_out;

  char* ws = (char*)d_ws;
  const size_t MB = 1ull<<20;
  u16*   qp     = (u16*)(ws + 0*MB);    // K1->K2
  u16*   kp     = (u16*)(ws + 8*MB);    // K1->K2
  u16*   vnT    = (u16*)(ws + 16*MB);   // K1->K2
  u16*   ao     = (u16*)(ws + 24*MB);   // K2->K3 (8MB)
  u16*   xres16 = (u16*)(ws + 8*MB);    // K3->K4 (8MB, over kp)
  u16*   x16    = (u16*)(ws + 16*MB);   // K4->K5 (8MB, over vnT)
  u16*   wo16   = (u16*)(ws + 48*MB);
  u16*   wsq16  = (u16*)(ws + 50*MB);

  k_proj<<<dim3(N_/64, H_+2), 256, 0, stream>>>(query, key, value, Wq, Wk, Wv,
                                                qp, kp, vnT, Wo, Wsq, wo16, wsq16);
  k_attn<<<512, 256, 0, stream>>>(qp, kp, vnT, ao);
  k_gemm<0><<<256, 256, 0, stream>>>(ao, wo16, bo, query, (const u16*)nullptr, (float*)nullptr, xres16);
  k_ln  <<<N_, 256, 0, stream>>>(xres16, lnw, lnb, x16);
  k_gemm<1><<<256, 256, 0, stream>>>(x16, wsq16, bsq, (const float*)nullptr, x16, out, (u16*)nullptr);
}

// Round 13
// 106.839 us; speedup vs baseline: 1.6332x; 1.0184x over previous
//
#include <hip/hip_runtime.h>
#include <stdint.h>

#define B_ 2
#define S_ 2048
#define E_ 1024
#define H_ 16
#define HD_ 64
#define N_ (B_*S_)
#define BH_ (B_*H_)
#define GAMMA 0.01f

typedef __attribute__((ext_vector_type(8))) short bf16x8;
typedef __attribute__((ext_vector_type(4))) float f32x4;
typedef __attribute__((ext_vector_type(2))) float f32x2;
typedef __attribute__((ext_vector_type(16))) float f32x16;
typedef __attribute__((ext_vector_type(4))) unsigned int u32x4;
typedef unsigned short u16;
typedef unsigned int u32;

// byte-level XOR swizzle within a 128B row
#define SWZ(row, kb) ((kb) ^ (((row)&7)<<4))

__device__ __forceinline__ u16 f2bf(float f){
  union { float f; u32 u; } v; v.f = f;
  return (u16)((v.u + 0x7FFFu + ((v.u>>16)&1u)) >> 16);
}

__device__ __forceinline__ float bf2f(u16 u){
  union { u32 u; float f; } v; v.u = ((u32)u)<<16; return v.f;
}

__device__ __forceinline__ u32 cvt_pk_bf16(float lo, float hi){
  u32 r; asm("v_cvt_pk_bf16_f32 %0, %1, %2" : "=v"(r) : "v"(lo), "v"(hi)); return r;
}

// packed fp32x8 -> bf16x8 conversion (4 HW instructions)
__device__ __forceinline__ uint4 pack8(float4 a, float4 b){
  uint4 r;
  r.x = cvt_pk_bf16(a.x, a.y);
  r.y = cvt_pk_bf16(a.z, a.w);
  r.z = cvt_pk_bf16(b.x, b.y);
  r.w = cvt_pk_bf16(b.z, b.w);
  return r;
}

__device__ __forceinline__ bf16x8 ldfrag(const unsigned char* base, int row, int kbyte){
  return *reinterpret_cast<const bf16x8*>(base + row*128 + SWZ(row, kbyte));
}
// V tile has 256B rows; 16-slot swizzle
__device__ __forceinline__ bf16x8 ldfragV(const unsigned char* base, int row, int col){
  return *reinterpret_cast<const bf16x8*>(base + row*256 + (col ^ ((row&15)<<4)));
}

// async global->LDS, 16B/lane; LDS dest = wave-uniform base + lane*16 (linear),
// swizzling achieved by permuting the per-lane SOURCE address
__device__ __forceinline__ void gl_lds16(const void* g, void* l){
  __builtin_amdgcn_global_load_lds(
      (const __attribute__((address_space(1))) unsigned int*)g,
      (__attribute__((address_space(3))) unsigned int*)l, 16, 0, 0);
}

// ---------------- K1: per-head QKV projection + xnorm(v), V transposed ----------------
// blockIdx.y >= H_: weight-conversion slabs (folded former k_cvt).
// This round: cvt_pk staging, vectorized Q/K epilogue via LDS, 48KB LDS (3 blocks/CU).
__device__ __forceinline__ void proj_mfma(const unsigned char* X, const unsigned char* W,
                                          int wid, int l15, int g4, f32x4 acc[4])
{
  f32x4 z = {0.f,0.f,0.f,0.f};
  acc[0]=z; acc[1]=z; acc[2]=z; acc[3]=z;
  #pragma unroll
  for (int kk=0;kk<2;++kk){
    int kbyte = kk*64 + g4*16;
    bf16x8 a = ldfrag(X, wid*16 + l15, kbyte);
    #pragma unroll
    for (int t=0;t<4;++t){
      bf16x8 w = ldfrag(W, t*16 + l15, kbyte);
      acc[t] = __builtin_amdgcn_mfma_f32_16x16x32_bf16(a, w, acc[t], 0, 0, 0);
    }
  }
}

__global__ __launch_bounds__(256) void k_proj(
    const float* __restrict__ qin, const float* __restrict__ kin, const float* __restrict__ vin,
    const float* __restrict__ Wq, const float* __restrict__ Wk, const float* __restrict__ Wv,
    u16* __restrict__ qp, u16* __restrict__ kp, u16* __restrict__ vnT,
    const float* __restrict__ Wo, const float* __restrict__ Wsq,
    u16* __restrict__ wo16, u16* __restrict__ wsq16)
{
  __shared__ alignas(16) unsigned char sm[49152];
  if (blockIdx.y >= H_){
    int cblk = (blockIdx.y - H_)*64 + blockIdx.x;
    int n4 = (E_*E_)/4;
    for (int i = cblk*256 + threadIdx.x; i < 2*n4; i += 128*256){
      const float4* src; ushort4* dst; int j;
      if (i < n4){ src=(const float4*)Wo;  dst=(ushort4*)wo16;  j=i; }
      else       { src=(const float4*)Wsq; dst=(ushort4*)wsq16; j=i-n4; }
      float4 v = src[j];
      ushort4 p; p.x=f2bf(v.x); p.y=f2bf(v.y); p.z=f2bf(v.z); p.w=f2bf(v.w);
      dst[j] = p;
    }
    return;
  }
  const int XQ=0, XK=8192, XV=16384, WQS=24576, WKS=32768, WVS=40960;
  int tid = threadIdx.x, lane = tid&63, wid = tid>>6;
  int l15 = lane&15, g4 = lane>>4;
  int tb = blockIdx.x*64;
  int h  = blockIdx.y;
  int b  = tb >> 11;
  int sbase = tb & 2047;
  int bh = b*H_ + h;

  { // stage X tiles (64 tok x 64 dims of head h) and W tiles, fp32 -> bf16 via cvt_pk
    int rl = tid>>2;
    int d0 = (tid&3)*16;
    const float* xs[3] = { qin, kin, vin };
    const float* wsrc[3] = { Wq, Wk, Wv };
    const int xoff[3] = {XQ,XK,XV}, woff[3] = {WQS,WKS,WVS};
    #pragma unroll
    for (int m3=0;m3<3;++m3){
      const float4* gx = reinterpret_cast<const float4*>(xs[m3] + (size_t)(tb+rl)*E_ + h*HD_ + d0);
      float4 a=gx[0], bb=gx[1], c=gx[2], d=gx[3];
      *(uint4*)(sm + xoff[m3] + rl*128 + SWZ(rl, d0*2))    = pack8(a,bb);
      *(uint4*)(sm + xoff[m3] + rl*128 + SWZ(rl, d0*2+16)) = pack8(c,d);
      const float4* gw = reinterpret_cast<const float4*>(wsrc[m3] + rl*64 + d0);
      float4 e=gw[0], f=gw[1], g2=gw[2], h2=gw[3];
      *(uint4*)(sm + woff[m3] + rl*128 + SWZ(rl, d0*2))    = pack8(e,f);
      *(uint4*)(sm + woff[m3] + rl*128 + SWZ(rl, d0*2+16)) = pack8(g2,h2);
    }
  }
  __syncthreads();

  // all three projections into registers (X/W LDS untouched until sync)
  f32x4 qacc[4], kacc[4], vacc[4];
  proj_mfma(sm+XQ, sm+WQS, wid, l15, g4, qacc);
  proj_mfma(sm+XK, sm+WKS, wid, l15, g4, kacc);
  proj_mfma(sm+XV, sm+WVS, wid, l15, g4, vacc);

  // xnorm(v) over head dim: reduce e^4 across the 16 col-lanes per token row
  {
    float p4r[4] = {0.f,0.f,0.f,0.f};
    #pragma unroll
    for (int t=0;t<4;++t)
      #pragma unroll
      for (int r=0;r<4;++r){ float e = vacc[t][r]; float e2 = e*e; p4r[r] += e2*e2; }
    #pragma unroll
    for (int r=0;r<4;++r){
      float p = p4r[r];
      p += __shfl_xor(p,1); p += __shfl_xor(p,2); p += __shfl_xor(p,4); p += __shfl_xor(p,8);
      p4r[r] = GAMMA / sqrtf(sqrtf(p));
    }
    #pragma unroll
    for (int t=0;t<4;++t)
      #pragma unroll
      for (int r=0;r<4;++r) vacc[t][r] *= p4r[r];
  }

  __syncthreads();   // X/W no longer needed; reuse XQ/XK/XV as output staging

  // write accs to LDS: Q,K token-major [tok][d]; V transposed [d][tok] (cvt_pk pairs)
  #pragma unroll
  for (int t=0;t<4;++t){
    int dd = t*16 + l15;
    #pragma unroll
    for (int r=0;r<4;++r){
      int tokl = wid*16 + g4*4 + r;
      *(u16*)(sm + XQ + tokl*128 + SWZ(tokl, dd*2)) = f2bf(qacc[t][r]);
      *(u16*)(sm + XK + tokl*128 + SWZ(tokl, dd*2)) = f2bf(kacc[t][r]);
    }
    #pragma unroll
    for (int r=0;r<4;r+=2){
      int tokl = wid*16 + g4*4 + r;
      *(u32*)(sm + XV + dd*128 + SWZ(dd, tokl*2)) = cvt_pk_bf16(vacc[t][r], vacc[t][r+1]);
    }
  }
  __syncthreads();

  { // vectorized global stores: 32B per thread per matrix
    int rl = tid>>2; int c2 = tid&3;
    uint4 q0 = *(const uint4*)(sm + XQ + rl*128 + SWZ(rl, c2*32));
    uint4 q1 = *(const uint4*)(sm + XQ + rl*128 + SWZ(rl, c2*32+16));
    size_t qg = ((size_t)bh*S_ + sbase + rl)*HD_ + c2*16;
    *(uint4*)(qp + qg)     = q0;
    *(uint4*)(qp + qg + 8) = q1;
    uint4 k0 = *(const uint4*)(sm + XK + rl*128 + SWZ(rl, c2*32));
    uint4 k1 = *(const uint4*)(sm + XK + rl*128 + SWZ(rl, c2*32+16));
    *(uint4*)(kp + qg)     = k0;
    *(uint4*)(kp + qg + 8) = k1;
    uint4 v0 = *(const uint4*)(sm + XV + rl*128 + SWZ(rl, c2*32));
    uint4 v1 = *(const uint4*)(sm + XV + rl*128 + SWZ(rl, c2*32+16));
    size_t vg = ((size_t)bh*HD_ + rl)*S_ + sbase + c2*16;
    *(uint4*)(vnT + vg)     = v0;
    *(uint4*)(vnT + vg + 8) = v1;
  }
}

// ---------------- K2: flash attention, KVBLK=128, Fq=2 (round-9 version, best known) ----------------
__global__ __launch_bounds__(256, 2) void k_attn(
    const u16* __restrict__ qp, const u16* __restrict__ kp,
    const u16* __restrict__ vnT, u16* __restrict__ ao)
{
  __shared__ alignas(128) unsigned char sm[65536];   // 2 x (K 16KB + V 16KB)
  char* smc = (char*)sm;
  int tid = threadIdx.x, lane = tid&63, wv = tid>>6;
  int l31 = lane&31, hi = lane>>5;
  int qi = wv>>1, kj = wv&1;
  int L = blockIdx.x;
  int xcd = L&7, iw = L>>3;            // iw 0..63
  int bh = xcd*4 + (iw>>4);            // consecutive iw share bh (L1/L2 reuse)
  int qx = iw&15;
  int qb = qx*128;
  int b = bh>>4, h = bh&15;
  const u16* Kb = kp  + (size_t)bh*S_*HD_;
  const u16* Vb = vnT + (size_t)bh*HD_*S_;
  const u16* Qb = qp  + (size_t)bh*S_*HD_;
  int q0 = qb + qi*64;

  bf16x8 qf[2][4];
  #pragma unroll
  for (int f=0;f<2;++f)
    #pragma unroll
    for (int kk=0;kk<4;++kk)
      qf[f][kk] = *reinterpret_cast<const bf16x8*>(Qb + (size_t)(q0 + f*32 + l31)*HD_ + kk*16 + hi*8);

  f32x16 z16 = {};
  f32x16 o[2][2];
  #pragma unroll
  for (int f=0;f<2;++f){ o[f][0] = z16; o[f][1] = z16; }
  f32x2 p4a[2] = {{0.f,0.f},{0.f,0.f}};
  f32x2 p4b[2] = {{0.f,0.f},{0.f,0.f}};

  const char* kSrcC[4]; const char* vSrcC[4];
  #pragma unroll
  for (int c=0;c<4;++c){
    int rk = wv*32 + c*8 + (lane>>3);
    int ck = ((lane&7)*16) ^ ((rk&7)<<4);
    kSrcC[c] = (const char*)Kb + (size_t)rk*128 + ck;
    int rv = wv*16 + c*4 + (lane>>4);
    int cv = ((lane&15)*16) ^ ((rv&15)<<4);
    vSrcC[c] = (const char*)Vb + (size_t)rv*4096 + cv;
  }

  auto STAGE = [&](int bsel, int kt){
    char* db = smc + bsel*32768 + wv*4096;
    #pragma unroll
    for (int c=0;c<4;++c) gl_lds16(kSrcC[c] + (size_t)kt*16384, db + c*1024);
    #pragma unroll
    for (int c=0;c<4;++c) gl_lds16(vSrcC[c] + (size_t)kt*256,   db + 16384 + c*1024);
  };

  auto PACK = [&](const f32x16& e, u32 (&w)[4][2], f32x2& pa){
    #pragma unroll
    for (int j=0;j<8;++j){
      const int g=j>>1, i=j&1;
      float a = e[4*g+2*i], c = e[4*g+2*i+1];
      f32x2 pr = {a, c};
      f32x2 e2;
      asm("v_pk_mul_f32 %0, %1, %1" : "=v"(e2) : "v"(pr));
      asm("v_pk_fma_f32 %0, %1, %1, %0" : "+v"(pa) : "v"(e2));
      w[g][i] = cvt_pk_bf16(a, c);
    }
  };
  auto AFRAG = [&](u32 (&w)[4][2], int s) -> bf16x8 {
    u32 a0 = w[2*s][0], b0 = w[2*s+1][0];
    u32 a1 = w[2*s][1], b1 = w[2*s+1][1];
    asm("v_permlane32_swap_b32 %0, %1" : "+v"(a0), "+v"(b0));
    asm("v_permlane32_swap_b32 %0, %1" : "+v"(a1), "+v"(b1));
    u32x4 fw = {a0, a1, b0, b1};
    return __builtin_bit_cast(bf16x8, fw);
  };

  auto QK = [&](const unsigned char* K_, int s2, f32x16& E0, f32x16& E1){
    bf16x8 ka[4];
    #pragma unroll
    for (int kk=0;kk<4;++kk) ka[kk] = ldfrag(K_, kj*64 + s2*32 + l31, kk*32 + hi*16);
    E0 = z16; E1 = z16;
    __builtin_amdgcn_s_setprio(1);
    #pragma unroll
    for (int kk=0;kk<4;++kk){
      E0 = __builtin_amdgcn_mfma_f32_32x32x16_bf16(ka[kk], qf[0][kk], E0, 0,0,0);
      E1 = __builtin_amdgcn_mfma_f32_32x32x16_bf16(ka[kk], qf[1][kk], E1, 0,0,0);
    }
    __builtin_amdgcn_s_setprio(0);
  };

  auto PVF = [&](const unsigned char* V_, int s2, u32 (&w0)[4][2], u32 (&w1)[4][2]){
    bf16x8 vb[2][2];
    #pragma unroll
    for (int s=0;s<2;++s){
      vb[s][0] = ldfragV(V_, l31,    kj*128 + s2*64 + s*32 + hi*16);
      vb[s][1] = ldfragV(V_, 32+l31, kj*128 + s2*64 + s*32 + hi*16);
    }
    __builtin_amdgcn_s_setprio(1);
    #pragma unroll
    for (int s=0;s<2;++s){
      bf16x8 ef0 = AFRAG(w0, s);
      bf16x8 ef1 = AFRAG(w1, s);
      o[0][0] = __builtin_amdgcn_mfma_f32_32x32x16_bf16(ef0, vb[s][0], o[0][0], 0,0,0);
      o[0][1] = __builtin_amdgcn_mfma_f32_32x32x16_bf16(ef0, vb[s][1], o[0][1], 0,0,0);
      o[1][0] = __builtin_amdgcn_mfma_f32_32x32x16_bf16(ef1, vb[s][0], o[1][0], 0,0,0);
      o[1][1] = __builtin_amdgcn_mfma_f32_32x32x16_bf16(ef1, vb[s][1], o[1][1], 0,0,0);
    }
    __builtin_amdgcn_s_setprio(0);
  };

  const int NT = S_/128;   // 16
  STAGE(0, 0); STAGE(1, 1);

  f32x16 eA0, eA1, eB0, eB1;
  u32 wA0[4][2], wA1[4][2], wB0[4][2], wB1[4][2];

  #pragma unroll 1
  for (int t=0; t<NT; ++t){
    if (t < NT-1) { asm volatile("s_waitcnt vmcnt(8)" ::: "memory"); }
    else          { asm volatile("s_waitcnt vmcnt(0)" ::: "memory"); }
    __builtin_amdgcn_s_barrier();
    asm volatile("" ::: "memory");
    const unsigned char* K_ = sm + (t&1)*32768;
    const unsigned char* V_ = K_ + 16384;

    QK(K_, 0, eA0, eA1);
    QK(K_, 1, eB0, eB1);
    PACK(eA0, wA0, p4a[0]);
    PACK(eA1, wA1, p4a[1]);
    PVF(V_, 0, wA0, wA1);
    PACK(eB0, wB0, p4b[0]);
    PACK(eB1, wB1, p4b[1]);
    PVF(V_, 1, wB0, wB1);

    asm volatile("" ::: "memory");
    __builtin_amdgcn_s_barrier();
    asm volatile("" ::: "memory");
    if (t+2 < NT) STAGE(t&1, t+2);
  }

  float p4f[2];
  #pragma unroll
  for (int f=0;f<2;++f) p4f[f] = p4a[f].x + p4a[f].y + p4b[f].x + p4b[f].y;

  __syncthreads();
  float* red  = (float*)smc;
  float* redp = (float*)(smc + 32768);
  if (kj==1){
    #pragma unroll
    for (int f=0;f<2;++f){
      #pragma unroll
      for (int ds=0;ds<2;++ds){
        float* dst = red + ((((qi*2+f)*2+ds)*64 + lane)*16);
        #pragma unroll
        for (int r4=0;r4<4;++r4)
          *(float4*)(dst + r4*4) = make_float4(o[f][ds][r4*4],o[f][ds][r4*4+1],o[f][ds][r4*4+2],o[f][ds][r4*4+3]);
      }
      redp[(qi*2+f)*64 + lane] = p4f[f];
    }
  }
  __syncthreads();
  if (kj==0){
    #pragma unroll
    for (int f=0;f<2;++f){
      #pragma unroll
      for (int ds=0;ds<2;++ds){
        const float* srcp = red + ((((qi*2+f)*2+ds)*64 + lane)*16);
        #pragma unroll
        for (int r4=0;r4<4;++r4){
          float4 t = *(const float4*)(srcp + r4*4);
          o[f][ds][r4*4]+=t.x; o[f][ds][r4*4+1]+=t.y; o[f][ds][r4*4+2]+=t.z; o[f][ds][r4*4+3]+=t.w;
        }
      }
      p4f[f] += redp[(qi*2+f)*64 + lane];
      p4f[f] += __shfl_xor(p4f[f], 32);
    }
    float sc0 = GAMMA * rsqrtf(sqrtf(p4f[0]));
    float sc1 = GAMMA * rsqrtf(sqrtf(p4f[1]));
    #pragma unroll
    for (int f=0;f<2;++f){
      #pragma unroll
      for (int r=0;r<16;++r){
        int qrow = (r&3) + 8*(r>>2) + 4*hi;
        float scr = __shfl(f==0 ? sc0 : sc1, qrow);
        size_t n = (size_t)b*S_ + q0 + f*32 + qrow;
        u16* dst = ao + n*E_ + h*HD_;
        dst[l31]    = f2bf(o[f][0][r] * scr);
        dst[32+l31] = f2bf(o[f][1][r] * scr);
      }
    }
  }
}

// ---------------- K3/K5: 128x128-tile bf16 GEMM, 64x64 per wave (1:1 MFMA:ds_read) ----------------
template<int MODE>
__global__ __launch_bounds__(256, 2) void k_gemm(
    const u16* __restrict__ A, const u16* __restrict__ Bw,
    const float* __restrict__ bias, const float* __restrict__ auxf,
    const u16* __restrict__ aux16, float* __restrict__ out32, u16* __restrict__ out16)
{
  __shared__ alignas(128) unsigned char sm[65536];   // 2 x (A 16KB + B 16KB)
  char* smc = (char*)sm;
  int tid = threadIdx.x, lane = tid&63, wv = tid>>6;
  int l31 = lane&31, hi = lane>>5;
  int wr = wv>>1, wc = wv&1;
  int LL = (blockIdx.x & 7)*32 + (blockIdx.x >> 3);
  int mt = LL >> 3, nt = LL & 7;                      // 32 m-tiles x 8 n-tiles
  int m0 = mt*128, n0 = nt*128;

  const char* aS[4]; const char* bS[4];
  #pragma unroll
  for (int c=0;c<4;++c){
    int off = wv*4096 + c*1024 + lane*16;
    int r = off>>7, cl = off&127;
    int cs = cl ^ ((r&7)<<4);
    aS[c] = (const char*)A  + ((size_t)(m0+r)*E_)*2 + cs;
    bS[c] = (const char*)Bw + ((size_t)(n0+r)*E_)*2 + cs;
  }

  auto STAGE = [&](int bsel, int t){
    char* db = smc + bsel*32768 + wv*4096;
    size_t kb2 = (size_t)t*128;
    #pragma unroll
    for (int c=0;c<4;++c) gl_lds16(aS[c] + kb2, db + c*1024);
    #pragma unroll
    for (int c=0;c<4;++c) gl_lds16(bS[c] + kb2, db + 16384 + c*1024);
  };

  f32x16 acc[2][2] = {{{}, {}}, {{}, {}}};

  const int NK = E_/64;   // 16
  STAGE(0, 0); STAGE(1, 1);

  #pragma unroll 1
  for (int t=0; t<NK; ++t){
    if (t < NK-1) { asm volatile("s_waitcnt vmcnt(8)" ::: "memory"); }
    else          { asm volatile("s_waitcnt vmcnt(0)" ::: "memory"); }
    __builtin_amdgcn_s_barrier();
    asm volatile("" ::: "memory");

    const unsigned char* Ap_ = sm + (t&1)*32768;
    const unsigned char* Bp_ = Ap_ + 16384;
    #pragma unroll
    for (int kk=0;kk<4;++kk){
      int kbyte = kk*32 + hi*16;
      bf16x8 a0 = ldfrag(Ap_, wr*64 + l31,      kbyte);
      bf16x8 a1 = ldfrag(Ap_, wr*64 + 32 + l31, kbyte);
      bf16x8 b0 = ldfrag(Bp_, wc*64 + l31,      kbyte);
      bf16x8 b1 = ldfrag(Bp_, wc*64 + 32 + l31, kbyte);
      __builtin_amdgcn_s_setprio(1);
      acc[0][0] = __builtin_amdgcn_mfma_f32_32x32x16_bf16(a0, b0, acc[0][0], 0,0,0);
      acc[0][1] = __builtin_amdgcn_mfma_f32_32x32x16_bf16(a0, b1, acc[0][1], 0,0,0);
      acc[1][0] = __builtin_amdgcn_mfma_f32_32x32x16_bf16(a1, b0, acc[1][0], 0,0,0);
      acc[1][1] = __builtin_amdgcn_mfma_f32_32x32x16_bf16(a1, b1, acc[1][1], 0,0,0);
      __builtin_amdgcn_s_setprio(0);
    }

    asm volatile("" ::: "memory");
    __builtin_amdgcn_s_barrier();
    asm volatile("" ::: "memory");
    if (t+2 < NK) STAGE(t&1, t+2);
  }

  #pragma unroll
  for (int cg=0;cg<2;++cg){
    int col = n0 + wc*64 + cg*32 + l31;
    float bi = bias[col];
    #pragma unroll
    for (int rg=0;rg<2;++rg)
      #pragma unroll
      for (int r=0;r<16;++r){
        int mrow = m0 + wr*64 + rg*32 + (r&3) + 8*(r>>2) + 4*hi;
        size_t idx = (size_t)mrow*E_ + col;
        float v = acc[rg][cg][r] + bi;
        if (MODE == 0){
          out16[idx] = f2bf(v + auxf[idx]);
        } else {
          float gg = 1.f/(1.f + __expf(-v));
          out32[idx] = bf2f(aux16[idx]) * gg;
        }
      }
  }
}

// ---------------- K4: LayerNorm over embed dim; bf16 in -> bf16 out ----------------
__global__ __launch_bounds__(256) void k_ln(
    const u16* __restrict__ xin, const float* __restrict__ lnw, const float* __restrict__ lnb,
    u16* __restrict__ xout)
{
  __shared__ float red[8];
  __shared__ float stats[2];
  int row = blockIdx.x, tid = threadIdx.x;
  ushort4 xr = reinterpret_cast<const ushort4*>(xin + (size_t)row*E_)[tid];
  float x0 = bf2f(xr.x), x1 = bf2f(xr.y), x2 = bf2f(xr.z), x3 = bf2f(xr.w);
  float s  = x0 + x1 + x2 + x3;
  float s2 = x0*x0 + x1*x1 + x2*x2 + x3*x3;
  #pragma unroll
  for (int m=1;m<64;m<<=1){ s += __shfl_xor(s,m); s2 += __shfl_xor(s2,m); }
  if ((tid&63)==0){ red[tid>>6] = s; red[4+(tid>>6)] = s2; }
  __syncthreads();
  if (tid==0){
    float ts  = red[0]+red[1]+red[2]+red[3];
    float ts2 = red[4]+red[5]+red[6]+red[7];
    float mu  = ts * (1.f/E_);
    float var = ts2 * (1.f/E_) - mu*mu;
    stats[0] = mu; stats[1] = rsqrtf(var + 1e-5f);
  }
  __syncthreads();
  float mu = stats[0], rstd = stats[1];
  float4 w  = reinterpret_cast<const float4*>(lnw)[tid];
  float4 bb = reinterpret_cast<const float4*>(lnb)[tid];
  ushort4 p;
  p.x = f2bf((x0-mu)*rstd*w.x + bb.x);
  p.y = f2bf((x1-mu)*rstd*w.y + bb.y);
  p.z = f2bf((x2-mu)*rstd*w.z + bb.z);
  p.w = f2bf((x3-mu)*rstd*w.w + bb.w);
  reinterpret_cast<ushort4*>(xout + (size_t)row*E_)[tid] = p;
}

// ---------------- host launch ----------------
extern "C" void kernel_launch(void* const* d_in, const int* in_sizes, int n_in,
                              void* d_out, int out_size, void* d_ws, size_t ws_size,
                              hipStream_t stream)
{
  const float* value = (const float*)d_in[0];
  const float* key   = (const float*)d_in[1];
  const float* query = (const float*)d_in[2];
  const float* Wq    = (const float*)d_in[3];
  const float* Wk    = (const float*)d_in[4];
  const float* Wv    = (const float*)d_in[5];
  const float* Wo    = (const float*)d_in[6];
  const float* bo    = (const float*)d_in[7];
  const float* lnw   = (const float*)d_in[8];
  const float* lnb   = (const float*)d_in[9];
  const float* Wsq   = (const float*)d_in[10];
  const float* bsq   = (const float*)d_in[11];
  float* out = (float*)d_out;

  char* ws = (char*)d_ws;
  const size_t MB = 1ull<<20;
  u16*   qp     = (u16*)(ws + 0*MB);    // K1->K2
  u16*   kp     = (u16*)(ws + 8*MB);    // K1->K2
  u16*   vnT    = (u16*)(ws + 16*MB);   // K1->K2
  u16*   ao     = (u16*)(ws + 24*MB);   // K2->K3 (8MB)
  u16*   xres16 = (u16*)(ws + 8*MB);    // K3->K4 (8MB, over kp)
  u16*   x16    = (u16*)(ws + 16*MB);   // K4->K5 (8MB, over vnT)
  u16*   wo16   = (u16*)(ws + 48*MB);
  u16*   wsq16  = (u16*)(ws + 50*MB);

  k_proj<<<dim3(N_/64, H_+2), 256, 0, stream>>>(query, key, value, Wq, Wk, Wv,
                                                qp, kp, vnT, Wo, Wsq, wo16, wsq16);
  k_attn<<<512, 256, 0, stream>>>(qp, kp, vnT, ao);
  k_gemm<0><<<256, 256, 0, stream>>>(ao, wo16, bo, query, (const u16*)nullptr, (float*)nullptr, xres16);
  k_ln  <<<N_, 256, 0, stream>>>(xres16, lnw, lnb, x16);
  k_gemm<1><<<256, 256, 0, stream>>>(x16, wsq16, bsq, (const float*)nullptr, x16, out, (u16*)nullptr);
}

// Round 14
// 104.544 us; speedup vs baseline: 1.6691x; 1.0220x over previous
//
#include <hip/hip_runtime.h>
#include <stdint.h>

#define B_ 2
#define S_ 2048
#define E_ 1024
#define H_ 16
#define HD_ 64
#define N_ (B_*S_)
#define BH_ (B_*H_)
#define GAMMA 0.01f

typedef __attribute__((ext_vector_type(8))) short bf16x8;
typedef __attribute__((ext_vector_type(4))) float f32x4;
typedef __attribute__((ext_vector_type(2))) float f32x2;
typedef __attribute__((ext_vector_type(16))) float f32x16;
typedef __attribute__((ext_vector_type(4))) unsigned int u32x4;
typedef unsigned short u16;
typedef unsigned int u32;

// byte-level XOR swizzle within a 128B row
#define SWZ(row, kb) ((kb) ^ (((row)&7)<<4))

__device__ __forceinline__ u16 f2bf(float f){
  union { float f; u32 u; } v; v.f = f;
  return (u16)((v.u + 0x7FFFu + ((v.u>>16)&1u)) >> 16);
}

__device__ __forceinline__ float bf2f(u16 u){
  union { u32 u; float f; } v; v.u = ((u32)u)<<16; return v.f;
}

__device__ __forceinline__ u32 cvt_pk_bf16(float lo, float hi){
  u32 r; asm("v_cvt_pk_bf16_f32 %0, %1, %2" : "=v"(r) : "v"(lo), "v"(hi)); return r;
}

// packed fp32x8 -> bf16x8 conversion (4 HW instructions)
__device__ __forceinline__ uint4 pack8(float4 a, float4 b){
  uint4 r;
  r.x = cvt_pk_bf16(a.x, a.y);
  r.y = cvt_pk_bf16(a.z, a.w);
  r.z = cvt_pk_bf16(b.x, b.y);
  r.w = cvt_pk_bf16(b.z, b.w);
  return r;
}

__device__ __forceinline__ bf16x8 ldfrag(const unsigned char* base, int row, int kbyte){
  return *reinterpret_cast<const bf16x8*>(base + row*128 + SWZ(row, kbyte));
}
// V tile has 256B rows; 16-slot swizzle
__device__ __forceinline__ bf16x8 ldfragV(const unsigned char* base, int row, int col){
  return *reinterpret_cast<const bf16x8*>(base + row*256 + (col ^ ((row&15)<<4)));
}

// async global->LDS, 16B/lane; LDS dest = wave-uniform base + lane*16 (linear),
// swizzling achieved by permuting the per-lane SOURCE address
__device__ __forceinline__ void gl_lds16(const void* g, void* l){
  __builtin_amdgcn_global_load_lds(
      (const __attribute__((address_space(1))) unsigned int*)g,
      (__attribute__((address_space(3))) unsigned int*)l, 16, 0, 0);
}

// ---------------- K1: per-head QKV projection + xnorm(v), V transposed ----------------
// blockIdx.y >= H_: weight-conversion slabs (folded former k_cvt).
__device__ __forceinline__ void proj_mfma(const unsigned char* X, const unsigned char* W,
                                          int wid, int l15, int g4, f32x4 acc[4])
{
  f32x4 z = {0.f,0.f,0.f,0.f};
  acc[0]=z; acc[1]=z; acc[2]=z; acc[3]=z;
  #pragma unroll
  for (int kk=0;kk<2;++kk){
    int kbyte = kk*64 + g4*16;
    bf16x8 a = ldfrag(X, wid*16 + l15, kbyte);
    #pragma unroll
    for (int t=0;t<4;++t){
      bf16x8 w = ldfrag(W, t*16 + l15, kbyte);
      acc[t] = __builtin_amdgcn_mfma_f32_16x16x32_bf16(a, w, acc[t], 0, 0, 0);
    }
  }
}

__global__ __launch_bounds__(256) void k_proj(
    const float* __restrict__ qin, const float* __restrict__ kin, const float* __restrict__ vin,
    const float* __restrict__ Wq, const float* __restrict__ Wk, const float* __restrict__ Wv,
    u16* __restrict__ qp, u16* __restrict__ kp, u16* __restrict__ vnT,
    const float* __restrict__ Wo, const float* __restrict__ Wsq,
    u16* __restrict__ wo16, u16* __restrict__ wsq16)
{
  __shared__ alignas(16) unsigned char sm[49152];
  if (blockIdx.y >= H_){
    int cblk = (blockIdx.y - H_)*64 + blockIdx.x;
    int n4 = (E_*E_)/4;
    for (int i = cblk*256 + threadIdx.x; i < 2*n4; i += 128*256){
      const float4* src; ushort4* dst; int j;
      if (i < n4){ src=(const float4*)Wo;  dst=(ushort4*)wo16;  j=i; }
      else       { src=(const float4*)Wsq; dst=(ushort4*)wsq16; j=i-n4; }
      float4 v = src[j];
      ushort4 p; p.x=f2bf(v.x); p.y=f2bf(v.y); p.z=f2bf(v.z); p.w=f2bf(v.w);
      dst[j] = p;
    }
    return;
  }
  const int XQ=0, XK=8192, XV=16384, WQS=24576, WKS=32768, WVS=40960;
  int tid = threadIdx.x, lane = tid&63, wid = tid>>6;
  int l15 = lane&15, g4 = lane>>4;
  int tb = blockIdx.x*64;
  int h  = blockIdx.y;
  int b  = tb >> 11;
  int sbase = tb & 2047;
  int bh = b*H_ + h;

  { // stage X tiles and W tiles, fp32 -> bf16 via cvt_pk
    int rl = tid>>2;
    int d0 = (tid&3)*16;
    const float* xs[3] = { qin, kin, vin };
    const float* wsrc[3] = { Wq, Wk, Wv };
    const int xoff[3] = {XQ,XK,XV}, woff[3] = {WQS,WKS,WVS};
    #pragma unroll
    for (int m3=0;m3<3;++m3){
      const float4* gx = reinterpret_cast<const float4*>(xs[m3] + (size_t)(tb+rl)*E_ + h*HD_ + d0);
      float4 a=gx[0], bb=gx[1], c=gx[2], d=gx[3];
      *(uint4*)(sm + xoff[m3] + rl*128 + SWZ(rl, d0*2))    = pack8(a,bb);
      *(uint4*)(sm + xoff[m3] + rl*128 + SWZ(rl, d0*2+16)) = pack8(c,d);
      const float4* gw = reinterpret_cast<const float4*>(wsrc[m3] + rl*64 + d0);
      float4 e=gw[0], f=gw[1], g2=gw[2], h2=gw[3];
      *(uint4*)(sm + woff[m3] + rl*128 + SWZ(rl, d0*2))    = pack8(e,f);
      *(uint4*)(sm + woff[m3] + rl*128 + SWZ(rl, d0*2+16)) = pack8(g2,h2);
    }
  }
  __syncthreads();

  f32x4 qacc[4], kacc[4], vacc[4];
  proj_mfma(sm+XQ, sm+WQS, wid, l15, g4, qacc);
  proj_mfma(sm+XK, sm+WKS, wid, l15, g4, kacc);
  proj_mfma(sm+XV, sm+WVS, wid, l15, g4, vacc);

  {
    float p4r[4] = {0.f,0.f,0.f,0.f};
    #pragma unroll
    for (int t=0;t<4;++t)
      #pragma unroll
      for (int r=0;r<4;++r){ float e = vacc[t][r]; float e2 = e*e; p4r[r] += e2*e2; }
    #pragma unroll
    for (int r=0;r<4;++r){
      float p = p4r[r];
      p += __shfl_xor(p,1); p += __shfl_xor(p,2); p += __shfl_xor(p,4); p += __shfl_xor(p,8);
      p4r[r] = GAMMA / sqrtf(sqrtf(p));
    }
    #pragma unroll
    for (int t=0;t<4;++t)
      #pragma unroll
      for (int r=0;r<4;++r) vacc[t][r] *= p4r[r];
  }

  __syncthreads();   // X/W no longer needed; reuse XQ/XK/XV as output staging

  #pragma unroll
  for (int t=0;t<4;++t){
    int dd = t*16 + l15;
    #pragma unroll
    for (int r=0;r<4;++r){
      int tokl = wid*16 + g4*4 + r;
      *(u16*)(sm + XQ + tokl*128 + SWZ(tokl, dd*2)) = f2bf(qacc[t][r]);
      *(u16*)(sm + XK + tokl*128 + SWZ(tokl, dd*2)) = f2bf(kacc[t][r]);
    }
    #pragma unroll
    for (int r=0;r<4;r+=2){
      int tokl = wid*16 + g4*4 + r;
      *(u32*)(sm + XV + dd*128 + SWZ(dd, tokl*2)) = cvt_pk_bf16(vacc[t][r], vacc[t][r+1]);
    }
  }
  __syncthreads();

  {
    int rl = tid>>2; int c2 = tid&3;
    uint4 q0 = *(const uint4*)(sm + XQ + rl*128 + SWZ(rl, c2*32));
    uint4 q1 = *(const uint4*)(sm + XQ + rl*128 + SWZ(rl, c2*32+16));
    size_t qg = ((size_t)bh*S_ + sbase + rl)*HD_ + c2*16;
    *(uint4*)(qp + qg)     = q0;
    *(uint4*)(qp + qg + 8) = q1;
    uint4 k0 = *(const uint4*)(sm + XK + rl*128 + SWZ(rl, c2*32));
    uint4 k1 = *(const uint4*)(sm + XK + rl*128 + SWZ(rl, c2*32+16));
    *(uint4*)(kp + qg)     = k0;
    *(uint4*)(kp + qg + 8) = k1;
    uint4 v0 = *(const uint4*)(sm + XV + rl*128 + SWZ(rl, c2*32));
    uint4 v1 = *(const uint4*)(sm + XV + rl*128 + SWZ(rl, c2*32+16));
    size_t vg = ((size_t)bh*HD_ + rl)*S_ + sbase + c2*16;
    *(uint4*)(vnT + vg)     = v0;
    *(uint4*)(vnT + vg + 8) = v1;
  }
}

// ---------------- K2: flash attention, KVBLK=128, Fq=2, ONE barrier/tile ----------------
// K in 3-buffer LDS (3x16KB @0), V in 2-buffer (2x16KB @49152) = 80KB/block,
// 2 blocks/CU. Per tile: [vmcnt(4); barrier] -> STAGE_V(t+1), STAGE_K(t+2) ->
// QK/PACK/PV. Single barrier => waves slip within the tile: fast wave's QK(t)
// overlaps slow wave's PV(t-1). FIFO vmcnt: queue at top of t = [K(t),V(t),K(t+1)],
// vmcnt(4) drains exactly K(t)+V(t). Never drains to 0 mid-loop.
__global__ __launch_bounds__(256, 2) void k_attn(
    const u16* __restrict__ qp, const u16* __restrict__ kp,
    const u16* __restrict__ vnT, u16* __restrict__ ao)
{
  __shared__ alignas(128) unsigned char sm[81920];   // K: 3x16KB @0; V: 2x16KB @49152
  char* smc = (char*)sm;
  int tid = threadIdx.x, lane = tid&63, wv = tid>>6;
  int l31 = lane&31, hi = lane>>5;
  int qi = wv>>1, kj = wv&1;
  int L = blockIdx.x;
  int xcd = L&7, iw = L>>3;            // iw 0..63
  int bh = xcd*4 + (iw>>4);            // consecutive iw share bh (L1/L2 reuse)
  int qx = iw&15;
  int qb = qx*128;
  int b = bh>>4, h = bh&15;
  const u16* Kb = kp  + (size_t)bh*S_*HD_;
  const u16* Vb = vnT + (size_t)bh*HD_*S_;
  const u16* Qb = qp  + (size_t)bh*S_*HD_;
  int q0 = qb + qi*64;

  bf16x8 qf[2][4];
  #pragma unroll
  for (int f=0;f<2;++f)
    #pragma unroll
    for (int kk=0;kk<4;++kk)
      qf[f][kk] = *reinterpret_cast<const bf16x8*>(Qb + (size_t)(q0 + f*32 + l31)*HD_ + kk*16 + hi*8);

  f32x16 z16 = {};
  f32x16 o[2][2];
  #pragma unroll
  for (int f=0;f<2;++f){ o[f][0] = z16; o[f][1] = z16; }
  f32x2 p4a[2] = {{0.f,0.f},{0.f,0.f}};
  f32x2 p4b[2] = {{0.f,0.f},{0.f,0.f}};

  const char* kSrcC[4]; const char* vSrcC[4];
  #pragma unroll
  for (int c=0;c<4;++c){
    int rk = wv*32 + c*8 + (lane>>3);
    int ck = ((lane&7)*16) ^ ((rk&7)<<4);
    kSrcC[c] = (const char*)Kb + (size_t)rk*128 + ck;
    int rv = wv*16 + c*4 + (lane>>4);
    int cv = ((lane&15)*16) ^ ((rv&15)<<4);
    vSrcC[c] = (const char*)Vb + (size_t)rv*4096 + cv;
  }

  auto STAGE_K = [&](int bsel, int kt){
    char* db = smc + bsel*16384 + wv*4096;
    #pragma unroll
    for (int c=0;c<4;++c) gl_lds16(kSrcC[c] + (size_t)kt*16384, db + c*1024);
  };
  auto STAGE_V = [&](int bsel, int kt){
    char* db = smc + 49152 + bsel*16384 + wv*4096;
    #pragma unroll
    for (int c=0;c<4;++c) gl_lds16(vSrcC[c] + (size_t)kt*256, db + c*1024);
  };

  auto PACK = [&](const f32x16& e, u32 (&w)[4][2], f32x2& pa){
    #pragma unroll
    for (int j=0;j<8;++j){
      const int g=j>>1, i=j&1;
      float a = e[4*g+2*i], c = e[4*g+2*i+1];
      f32x2 pr = {a, c};
      f32x2 e2;
      asm("v_pk_mul_f32 %0, %1, %1" : "=v"(e2) : "v"(pr));
      asm("v_pk_fma_f32 %0, %1, %1, %0" : "+v"(pa) : "v"(e2));
      w[g][i] = cvt_pk_bf16(a, c);
    }
  };
  auto AFRAG = [&](u32 (&w)[4][2], int s) -> bf16x8 {
    u32 a0 = w[2*s][0], b0 = w[2*s+1][0];
    u32 a1 = w[2*s][1], b1 = w[2*s+1][1];
    asm("v_permlane32_swap_b32 %0, %1" : "+v"(a0), "+v"(b0));
    asm("v_permlane32_swap_b32 %0, %1" : "+v"(a1), "+v"(b1));
    u32x4 fw = {a0, a1, b0, b1};
    return __builtin_bit_cast(bf16x8, fw);
  };

  auto QK = [&](const unsigned char* K_, int s2, f32x16& E0, f32x16& E1){
    bf16x8 ka[4];
    #pragma unroll
    for (int kk=0;kk<4;++kk) ka[kk] = ldfrag(K_, kj*64 + s2*32 + l31, kk*32 + hi*16);
    E0 = z16; E1 = z16;
    __builtin_amdgcn_s_setprio(1);
    #pragma unroll
    for (int kk=0;kk<4;++kk){
      E0 = __builtin_amdgcn_mfma_f32_32x32x16_bf16(ka[kk], qf[0][kk], E0, 0,0,0);
      E1 = __builtin_amdgcn_mfma_f32_32x32x16_bf16(ka[kk], qf[1][kk], E1, 0,0,0);
    }
    __builtin_amdgcn_s_setprio(0);
  };

  auto PVF = [&](const unsigned char* V_, int s2, u32 (&w0)[4][2], u32 (&w1)[4][2]){
    bf16x8 vb[2][2];
    #pragma unroll
    for (int s=0;s<2;++s){
      vb[s][0] = ldfragV(V_, l31,    kj*128 + s2*64 + s*32 + hi*16);
      vb[s][1] = ldfragV(V_, 32+l31, kj*128 + s2*64 + s*32 + hi*16);
    }
    __builtin_amdgcn_s_setprio(1);
    #pragma unroll
    for (int s=0;s<2;++s){
      bf16x8 ef0 = AFRAG(w0, s);
      bf16x8 ef1 = AFRAG(w1, s);
      o[0][0] = __builtin_amdgcn_mfma_f32_32x32x16_bf16(ef0, vb[s][0], o[0][0], 0,0,0);
      o[0][1] = __builtin_amdgcn_mfma_f32_32x32x16_bf16(ef0, vb[s][1], o[0][1], 0,0,0);
      o[1][0] = __builtin_amdgcn_mfma_f32_32x32x16_bf16(ef1, vb[s][0], o[1][0], 0,0,0);
      o[1][1] = __builtin_amdgcn_mfma_f32_32x32x16_bf16(ef1, vb[s][1], o[1][1], 0,0,0);
    }
    __builtin_amdgcn_s_setprio(0);
  };

  const int NT = S_/128;   // 16
  // prologue: issue K(0), V(0), K(1)  (order matters for FIFO vmcnt math)
  STAGE_K(0, 0); STAGE_V(0, 0); STAGE_K(1, 1);

  f32x16 eA0, eA1, eB0, eB1;
  u32 wA0[4][2], wA1[4][2], wB0[4][2], wB1[4][2];

  #pragma unroll 1
  for (int t=0; t<NT; ++t){
    if (t < NT-1) { asm volatile("s_waitcnt vmcnt(4)" ::: "memory"); }
    else          { asm volatile("s_waitcnt vmcnt(0)" ::: "memory"); }
    __builtin_amdgcn_s_barrier();      // the ONLY barrier per tile
    asm volatile("" ::: "memory");
    if (t+1 < NT) STAGE_V((t+1)&1, t+1);   // overwrites buffer last read at PV(t-1)
    if (t+2 < NT) STAGE_K((t+2)%3, t+2);   // 3-buf slot last read at QK(t-1)

    const unsigned char* K_ = sm + (t%3)*16384;
    const unsigned char* V_ = sm + 49152 + (t&1)*16384;

    QK(K_, 0, eA0, eA1);
    QK(K_, 1, eB0, eB1);
    PACK(eA0, wA0, p4a[0]);
    PACK(eA1, wA1, p4a[1]);
    PVF(V_, 0, wA0, wA1);
    PACK(eB0, wB0, p4b[0]);
    PACK(eB1, wB1, p4b[1]);
    PVF(V_, 1, wB0, wB1);
  }

  float p4f[2];
  #pragma unroll
  for (int f=0;f<2;++f) p4f[f] = p4a[f].x + p4a[f].y + p4b[f].x + p4b[f].y;

  __syncthreads();
  float* red  = (float*)smc;
  float* redp = (float*)(smc + 32768);
  if (kj==1){
    #pragma unroll
    for (int f=0;f<2;++f){
      #pragma unroll
      for (int ds=0;ds<2;++ds){
        float* dst = red + ((((qi*2+f)*2+ds)*64 + lane)*16);
        #pragma unroll
        for (int r4=0;r4<4;++r4)
          *(float4*)(dst + r4*4) = make_float4(o[f][ds][r4*4],o[f][ds][r4*4+1],o[f][ds][r4*4+2],o[f][ds][r4*4+3]);
      }
      redp[(qi*2+f)*64 + lane] = p4f[f];
    }
  }
  __syncthreads();
  if (kj==0){
    #pragma unroll
    for (int f=0;f<2;++f){
      #pragma unroll
      for (int ds=0;ds<2;++ds){
        const float* srcp = red + ((((qi*2+f)*2+ds)*64 + lane)*16);
        #pragma unroll
        for (int r4=0;r4<4;++r4){
          float4 t = *(const float4*)(srcp + r4*4);
          o[f][ds][r4*4]+=t.x; o[f][ds][r4*4+1]+=t.y; o[f][ds][r4*4+2]+=t.z; o[f][ds][r4*4+3]+=t.w;
        }
      }
      p4f[f] += redp[(qi*2+f)*64 + lane];
      p4f[f] += __shfl_xor(p4f[f], 32);
    }
    float sc0 = GAMMA * rsqrtf(sqrtf(p4f[0]));
    float sc1 = GAMMA * rsqrtf(sqrtf(p4f[1]));
    #pragma unroll
    for (int f=0;f<2;++f){
      #pragma unroll
      for (int r=0;r<16;++r){
        int qrow = (r&3) + 8*(r>>2) + 4*hi;
        float scr = __shfl(f==0 ? sc0 : sc1, qrow);
        size_t n = (size_t)b*S_ + q0 + f*32 + qrow;
        u16* dst = ao + n*E_ + h*HD_;
        dst[l31]    = f2bf(o[f][0][r] * scr);
        dst[32+l31] = f2bf(o[f][1][r] * scr);
      }
    }
  }
}

// ---------------- K3/K5: 128x128-tile bf16 GEMM, 64x64 per wave (1:1 MFMA:ds_read) ----------------
template<int MODE>
__global__ __launch_bounds__(256, 2) void k_gemm(
    const u16* __restrict__ A, const u16* __restrict__ Bw,
    const float* __restrict__ bias, const float* __restrict__ auxf,
    const u16* __restrict__ aux16, float* __restrict__ out32, u16* __restrict__ out16)
{
  __shared__ alignas(128) unsigned char sm[65536];   // 2 x (A 16KB + B 16KB)
  char* smc = (char*)sm;
  int tid = threadIdx.x, lane = tid&63, wv = tid>>6;
  int l31 = lane&31, hi = lane>>5;
  int wr = wv>>1, wc = wv&1;
  int LL = (blockIdx.x & 7)*32 + (blockIdx.x >> 3);
  int mt = LL >> 3, nt = LL & 7;                      // 32 m-tiles x 8 n-tiles
  int m0 = mt*128, n0 = nt*128;

  const char* aS[4]; const char* bS[4];
  #pragma unroll
  for (int c=0;c<4;++c){
    int off = wv*4096 + c*1024 + lane*16;
    int r = off>>7, cl = off&127;
    int cs = cl ^ ((r&7)<<4);
    aS[c] = (const char*)A  + ((size_t)(m0+r)*E_)*2 + cs;
    bS[c] = (const char*)Bw + ((size_t)(n0+r)*E_)*2 + cs;
  }

  auto STAGE = [&](int bsel, int t){
    char* db = smc + bsel*32768 + wv*4096;
    size_t kb2 = (size_t)t*128;
    #pragma unroll
    for (int c=0;c<4;++c) gl_lds16(aS[c] + kb2, db + c*1024);
    #pragma unroll
    for (int c=0;c<4;++c) gl_lds16(bS[c] + kb2, db + 16384 + c*1024);
  };

  f32x16 acc[2][2] = {{{}, {}}, {{}, {}}};

  const int NK = E_/64;   // 16
  STAGE(0, 0); STAGE(1, 1);

  #pragma unroll 1
  for (int t=0; t<NK; ++t){
    if (t < NK-1) { asm volatile("s_waitcnt vmcnt(8)" ::: "memory"); }
    else          { asm volatile("s_waitcnt vmcnt(0)" ::: "memory"); }
    __builtin_amdgcn_s_barrier();
    asm volatile("" ::: "memory");

    const unsigned char* Ap_ = sm + (t&1)*32768;
    const unsigned char* Bp_ = Ap_ + 16384;
    #pragma unroll
    for (int kk=0;kk<4;++kk){
      int kbyte = kk*32 + hi*16;
      bf16x8 a0 = ldfrag(Ap_, wr*64 + l31,      kbyte);
      bf16x8 a1 = ldfrag(Ap_, wr*64 + 32 + l31, kbyte);
      bf16x8 b0 = ldfrag(Bp_, wc*64 + l31,      kbyte);
      bf16x8 b1 = ldfrag(Bp_, wc*64 + 32 + l31, kbyte);
      __builtin_amdgcn_s_setprio(1);
      acc[0][0] = __builtin_amdgcn_mfma_f32_32x32x16_bf16(a0, b0, acc[0][0], 0,0,0);
      acc[0][1] = __builtin_amdgcn_mfma_f32_32x32x16_bf16(a0, b1, acc[0][1], 0,0,0);
      acc[1][0] = __builtin_amdgcn_mfma_f32_32x32x16_bf16(a1, b0, acc[1][0], 0,0,0);
      acc[1][1] = __builtin_amdgcn_mfma_f32_32x32x16_bf16(a1, b1, acc[1][1], 0,0,0);
      __builtin_amdgcn_s_setprio(0);
    }

    asm volatile("" ::: "memory");
    __builtin_amdgcn_s_barrier();
    asm volatile("" ::: "memory");
    if (t+2 < NK) STAGE(t&1, t+2);
  }

  #pragma unroll
  for (int cg=0;cg<2;++cg){
    int col = n0 + wc*64 + cg*32 + l31;
    float bi = bias[col];
    #pragma unroll
    for (int rg=0;rg<2;++rg)
      #pragma unroll
      for (int r=0;r<16;++r){
        int mrow = m0 + wr*64 + rg*32 + (r&3) + 8*(r>>2) + 4*hi;
        size_t idx = (size_t)mrow*E_ + col;
        float v = acc[rg][cg][r] + bi;
        if (MODE == 0){
          out16[idx] = f2bf(v + auxf[idx]);
        } else {
          float gg = 1.f/(1.f + __expf(-v));
          out32[idx] = bf2f(aux16[idx]) * gg;
        }
      }
  }
}

// ---------------- K4: LayerNorm over embed dim; bf16 in -> bf16 out ----------------
__global__ __launch_bounds__(256) void k_ln(
    const u16* __restrict__ xin, const float* __restrict__ lnw, const float* __restrict__ lnb,
    u16* __restrict__ xout)
{
  __shared__ float red[8];
  __shared__ float stats[2];
  int row = blockIdx.x, tid = threadIdx.x;
  ushort4 xr = reinterpret_cast<const ushort4*>(xin + (size_t)row*E_)[tid];
  float x0 = bf2f(xr.x), x1 = bf2f(xr.y), x2 = bf2f(xr.z), x3 = bf2f(xr.w);
  float s  = x0 + x1 + x2 + x3;
  float s2 = x0*x0 + x1*x1 + x2*x2 + x3*x3;
  #pragma unroll
  for (int m=1;m<64;m<<=1){ s += __shfl_xor(s,m); s2 += __shfl_xor(s2,m); }
  if ((tid&63)==0){ red[tid>>6] = s; red[4+(tid>>6)] = s2; }
  __syncthreads();
  if (tid==0){
    float ts  = red[0]+red[1]+red[2]+red[3];
    float ts2 = red[4]+red[5]+red[6]+red[7];
    float mu  = ts * (1.f/E_);
    float var = ts2 * (1.f/E_) - mu*mu;
    stats[0] = mu; stats[1] = rsqrtf(var + 1e-5f);
  }
  __syncthreads();
  float mu = stats[0], rstd = stats[1];
  float4 w  = reinterpret_cast<const float4*>(lnw)[tid];
  float4 bb = reinterpret_cast<const float4*>(lnb)[tid];
  ushort4 p;
  p.x = f2bf((x0-mu)*rstd*w.x + bb.x);
  p.y = f2bf((x1-mu)*rstd*w.y + bb.y);
  p.z = f2bf((x2-mu)*rstd*w.z + bb.z);
  p.w = f2bf((x3-mu)*rstd*w.w + bb.w);
  reinterpret_cast<ushort4*>(xout + (size_t)row*E_)[tid] = p;
}

// ---------------- host launch ----------------
extern "C" void kernel_launch(void* const* d_in, const int* in_sizes, int n_in,
                              void* d_out, int out_size, void* d_ws, size_t ws_size,
                              hipStream_t stream)
{
  const float* value = (const float*)d_in[0];
  const float* key   = (const float*)d_in[1];
  const float* query = (const float*)d_in[2];
  const float* Wq    = (const float*)d_in[3];
  const float* Wk    = (const float*)d_in[4];
  const float* Wv    = (const float*)d_in[5];
  const float* Wo    = (const float*)d_in[6];
  const float* bo    = (const float*)d_in[7];
  const float* lnw   = (const float*)d_in[8];
  const float* lnb   = (const float*)d_in[9];
  const float* Wsq   = (const float*)d_in[10];
  const float* bsq   = (const float*)d_in[11];
  float* out = (float*)d_out;

  char* ws = (char*)d_ws;
  const size_t MB = 1ull<<20;
  u16*   qp     = (u16*)(ws + 0*MB);    // K1->K2
  u16*   kp     = (u16*)(ws + 8*MB);    // K1->K2
  u16*   vnT    = (u16*)(ws + 16*MB);   // K1->K2
  u16*   ao     = (u16*)(ws + 24*MB);   // K2->K3 (8MB)
  u16*   xres16 = (u16*)(ws + 8*MB);    // K3->K4 (8MB, over kp)
  u16*   x16    = (u16*)(ws + 16*MB);   // K4->K5 (8MB, over vnT)
  u16*   wo16   = (u16*)(ws + 48*MB);
  u16*   wsq16  = (u16*)(ws + 50*MB);

  k_proj<<<dim3(N_/64, H_+2), 256, 0, stream>>>(query, key, value, Wq, Wk, Wv,
                                                qp, kp, vnT, Wo, Wsq, wo16, wsq16);
  k_attn<<<512, 256, 0, stream>>>(qp, kp, vnT, ao);
  k_gemm<0><<<256, 256, 0, stream>>>(ao, wo16, bo, query, (const u16*)nullptr, (float*)nullptr, xres16);
  k_ln  <<<N_, 256, 0, stream>>>(xres16, lnw, lnb, x16);
  k_gemm<1><<<256, 256, 0, stream>>>(x16, wsq16, bsq, (const float*)nullptr, x16, out, (u16*)nullptr);
}